// Round 7
// baseline (2333.806 us; speedup 1.0000x reference)
//
#include <hip/hip_runtime.h>

#define BB 8
#define NN 4096
#define KK 10
typedef unsigned long long u64;

__device__ __forceinline__ float lrelu(float v){ return v >= 0.f ? v : 0.2f*v; }
__device__ __forceinline__ float bc(float v, int l){
  return __int_as_float(__builtin_amdgcn_readlane(__float_as_int(v), l));
}
__device__ __forceinline__ unsigned fenc(float f){
  unsigned u = __float_as_uint(f);
  return u ^ (((unsigned)((int)u >> 31)) | 0x80000000u);
}
__device__ __forceinline__ float fdec(unsigned e){
  return (e & 0x80000000u) ? __uint_as_float(e & 0x7fffffffu) : __uint_as_float(~e);
}
__device__ __forceinline__ u64 shflx_u64(u64 x, int d){
  unsigned lo = __shfl_xor((unsigned)x, d, 64);
  unsigned hi = __shfl_xor((unsigned)(x >> 32), d, 64);
  return ((u64)hi << 32) | lo;
}

// ---------------- weight transposes (one-time tiny prep) ----------------
__global__ __launch_bounds__(256) void prep_k(
    const float* __restrict__ W1, const float* __restrict__ W2, const float* __restrict__ W3,
    const float* __restrict__ W4, const float* __restrict__ W5, const float* __restrict__ W8,
    float* __restrict__ W1T, float* __restrict__ W2T, float* __restrict__ W3T,
    float* __restrict__ W4T, float* __restrict__ W5T, float* __restrict__ W8T)
{
  const int t = blockIdx.x*256 + threadIdx.x;
  const int stride = gridDim.x*256;
  for (int i=t; i<64*14; i+=stride){ int o=i/14, c=i%14; W1T[c*64+o]=W1[i]; }
  for (int i=t; i<64*64; i+=stride){ int o=i>>6, c=i&63; W2T[c*64+o]=W2[i]; }
  for (int i=t; i<64*128; i+=stride){ int o=i>>7, c=i&127; W3T[c*64+o]=W3[i]; }
  for (int i=t; i<64*64; i+=stride){ int o=i>>6, c=i&63; W4T[c*64+o]=W4[i]; }
  for (int i=t; i<64*128; i+=stride){ int o=i>>7, c=i&127; W5T[c*64+o]=W5[i]; }
  for (int i=t; i<128*1024; i+=stride){ int o=i>>10, c=i&1023; W8T[c*128+o]=W8[i]; }
}

// ---------------- knn over first 2 channels (candidate-split halves) ----------------
__global__ __launch_bounds__(256) void knn2d_k(const float* __restrict__ x, u64* __restrict__ pk)
{
  __shared__ float px[2048], py[2048], pxx[2048];
  const int tid = threadIdx.x;
  const int b  = blockIdx.x >> 7;
  const int qt = (blockIdx.x >> 1) & 63;
  const int h  = blockIdx.x & 1;
  const int q0 = qt*64;
  const int m0g = h*2048;
  const float* xb = x + (size_t)b*7*NN;
  for (int m = tid; m < 2048; m += 256){
    float a = xb[m0g + m], c = xb[NN + m0g + m];
    px[m] = a; py[m] = c; pxx[m] = a*a + c*c;
  }
  __syncthreads();

  const int ty = tid >> 4, tx = tid & 15;
  const int qr = ty*4;
  float qx4[4], qy4[4], q24[4];
  #pragma unroll
  for (int i=0;i<4;i++){
    float a = xb[q0+qr+i], c = xb[NN + q0+qr+i];
    qx4[i] = a; qy4[i] = c; q24[i] = a*a + c*c;
  }

  u64 bk[4][KK]; u64 tau[4];
  #pragma unroll
  for (int i=0;i<4;i++){
    tau[i] = 0ull;
    #pragma unroll
    for (int s=0;s<KK;s++) bk[i][s] = 0ull;
  }

  for (int ot=0; ot<16; ot++){
    #pragma unroll
    for (int j=0;j<8;j++){
      const int ml = ot*128 + j*16 + tx;
      const float cmx = px[ml], cmy = py[ml], cm2 = pxx[ml];
      const unsigned mk = ~(unsigned)(m0g + ml);
      #pragma unroll
      for (int i=0;i<4;i++){
        float dot = qx4[i]*cmx + qy4[i]*cmy;
        float v = (-q24[i]) - (-2.f*dot) - cm2;
        u64 key = ((u64)fenc(v) << 32) | mk;
        if (key >= tau[i]){
          if (key > bk[i][KK-1]){
            bk[i][KK-1] = key;
            #pragma unroll
            for (int s=KK-1;s>0;s--){
              if (bk[i][s] > bk[i][s-1]){ u64 t=bk[i][s]; bk[i][s]=bk[i][s-1]; bk[i][s-1]=t; }
            }
          }
        }
      }
    }
    #pragma unroll
    for (int i=0;i<4;i++){
      u64 t = bk[i][KK-1];
      t = t > shflx_u64(t,1) ? t : shflx_u64(t,1);
      t = t > shflx_u64(t,2) ? t : shflx_u64(t,2);
      t = t > shflx_u64(t,4) ? t : shflx_u64(t,4);
      t = t > shflx_u64(t,8) ? t : shflx_u64(t,8);
      tau[i] = t;
    }
  }

  #pragma unroll
  for (int i=0;i<4;i++){
    #pragma unroll
    for (int k=0;k<KK;k++){
      u64 best = bk[i][0];
      #pragma unroll
      for (int d=1; d<16; d<<=1){
        u64 o = shflx_u64(best, d);
        if (o > best) best = o;
      }
      if (bk[i][0] == best){
        #pragma unroll
        for (int s=0;s<KK-1;s++) bk[i][s] = bk[i][s+1];
        bk[i][KK-1] = 0ull;
      }
      if (tx == 0) pk[(((size_t)b*NN + q0 + qr + i)*2 + h)*KK + k] = best;
    }
  }
}

// ---------------- knn over 64 channels, candidate-split halves ----------------
// 64-cand tiles: LDS = Qs 16.6KB + Cs 16.6KB + ~0.6KB = 33.8KB -> 4 blocks/CU by LDS.
// NO min-waves launch-bounds hint: round 6 showed (256,4) forces VGPR=64 and spills
// the top-k arrays to scratch (FETCH 21->506MB). Natural ~100 VGPR sits in the
// <=128 bucket = 4 waves/SIMD = 16 waves/CU, which is exactly the LDS-allowed residency.
__global__ __launch_bounds__(256) void knn64_k(const float* __restrict__ xt, u64* __restrict__ pk)
{
  __shared__ float Qs[16*65*4];     // 16640 B
  __shared__ float Cs[16*65*4];     // 16640 B
  __shared__ float qxx[64];
  __shared__ float cxx[64];
  const int tid = threadIdx.x;
  const int b  = blockIdx.x >> 7;
  const int qt = (blockIdx.x >> 1) & 63;
  const int h  = blockIdx.x & 1;
  const int q0 = qt*64;
  const int m0g = h*2048;
  const float* xb = xt + (size_t)b*NN*64;

  #pragma unroll
  for (int r=0;r<4;r++){
    int i = tid + r*256;
    int p = i >> 4, c4 = i & 15;
    float4 v = *(const float4*)(xb + (size_t)(q0+p)*64 + c4*4);
    *(float4*)(&Qs[c4*260 + p*4]) = v;
  }
  __syncthreads();
  if (tid < 64){
    float ss = 0.f;
    #pragma unroll
    for (int c4=0;c4<16;c4++){
      float4 v = *(const float4*)(&Qs[c4*260 + tid*4]);
      ss += v.x*v.x + v.y*v.y + v.z*v.z + v.w*v.w;
    }
    qxx[tid] = ss;
  }
  __syncthreads();

  const int ty = tid >> 4, tx = tid & 15;
  const int qr = ty*4;
  float qx4[4];
  #pragma unroll
  for (int i=0;i<4;i++) qx4[i] = qxx[qr+i];

  const float* cvb = &Cs[tx*4];     // one base for all cv reads of a tile
  const float* qvb = &Qs[qr*4];     // one base for all qv reads of a tile

  u64 bk[4][KK]; u64 tau[4];
  #pragma unroll
  for (int i=0;i<4;i++){
    tau[i] = 0ull;
    #pragma unroll
    for (int s=0;s<KK;s++) bk[i][s] = 0ull;
  }

  for (int ct=0; ct<32; ct++){
    const int m0 = m0g + ct*64;
    __syncthreads();
    #pragma unroll
    for (int r=0;r<4;r++){
      int i = tid + r*256;
      int p = i >> 4, c4 = i & 15;
      float4 v = *(const float4*)(xb + (size_t)(m0+p)*64 + c4*4);
      *(float4*)(&Cs[c4*260 + ((p&3)*16 + (p>>2))*4]) = v;
      float ss = v.x*v.x + v.y*v.y + v.z*v.z + v.w*v.w;
      ss += __shfl_xor(ss, 1, 64);
      ss += __shfl_xor(ss, 2, 64);
      ss += __shfl_xor(ss, 4, 64);
      ss += __shfl_xor(ss, 8, 64);
      if (c4 == 0) cxx[p] = ss;
    }
    __syncthreads();

    float acc[4][4];
    #pragma unroll
    for (int i=0;i<4;i++){
      #pragma unroll
      for (int j=0;j<4;j++) acc[i][j] = 0.f;
    }

    #pragma unroll 4
    for (int c4=0;c4<16;c4++){
      float4 qv[4];
      #pragma unroll
      for (int i=0;i<4;i++) qv[i] = *(const float4*)(qvb + c4*260 + i*4);
      #pragma unroll
      for (int j=0;j<4;j++){
        float4 cv = *(const float4*)(cvb + c4*260 + j*64);
        #pragma unroll
        for (int i=0;i<4;i++){
          acc[i][j] += qv[i].x*cv.x;
          acc[i][j] += qv[i].y*cv.y;
          acc[i][j] += qv[i].z*cv.z;
          acc[i][j] += qv[i].w*cv.w;
        }
      }
    }

    #pragma unroll
    for (int j=0;j<4;j++){
      const int m = m0 + tx*4 + j;
      const float cx = cxx[tx*4+j];
      const unsigned mk = ~(unsigned)m;
      #pragma unroll
      for (int i=0;i<4;i++){
        float v = (-qx4[i]) - (-2.f*acc[i][j]) - cx;
        u64 key = ((u64)fenc(v) << 32) | mk;
        if (key >= tau[i]){
          if (key > bk[i][KK-1]){
            bk[i][KK-1] = key;
            #pragma unroll
            for (int s=KK-1;s>0;s--){
              if (bk[i][s] > bk[i][s-1]){ u64 t=bk[i][s]; bk[i][s]=bk[i][s-1]; bk[i][s-1]=t; }
            }
          }
        }
      }
    }
    #pragma unroll
    for (int i=0;i<4;i++){
      u64 t = bk[i][KK-1];
      t = t > shflx_u64(t,1) ? t : shflx_u64(t,1);
      t = t > shflx_u64(t,2) ? t : shflx_u64(t,2);
      t = t > shflx_u64(t,4) ? t : shflx_u64(t,4);
      t = t > shflx_u64(t,8) ? t : shflx_u64(t,8);
      tau[i] = t;
    }
  }

  #pragma unroll
  for (int i=0;i<4;i++){
    #pragma unroll
    for (int k=0;k<KK;k++){
      u64 best = bk[i][0];
      #pragma unroll
      for (int d=1; d<16; d<<=1){
        u64 o = shflx_u64(best, d);
        if (o > best) best = o;
      }
      if (bk[i][0] == best){
        #pragma unroll
        for (int s=0;s<KK-1;s++) bk[i][s] = bk[i][s+1];
        bk[i][KK-1] = 0ull;
      }
      if (tx == 0) pk[(((size_t)b*NN + q0 + qr + i)*2 + h)*KK + k] = best;
    }
  }
}

// ---------------- merge two sorted-desc 10-key halves -> final idx ----------------
__global__ __launch_bounds__(256) void kmerge_k(const u64* __restrict__ pk, int* __restrict__ idxo)
{
  const int q = blockIdx.x*256 + threadIdx.x;   // q < BB*NN
  const u64* A = pk + (size_t)q*(2*KK);
  int* op = idxo + (size_t)q*KK;
  int ia = 0, ib = 0;
  #pragma unroll
  for (int k=0;k<KK;k++){
    u64 a = (ia < KK) ? A[ia] : 0ull;
    u64 b2 = (ib < KK) ? A[KK+ib] : 0ull;
    if (a >= b2){ op[k] = (int)(~(unsigned)a); ia++; }
    else        { op[k] = (int)(~(unsigned)b2); ib++; }
  }
}

// ---------------- edge conv 1: graph_feature1 + W1 + W2 + mean ----------------
__global__ __launch_bounds__(256) void edge1_k(const float* __restrict__ x, const int* __restrict__ idx,
    const float* __restrict__ W1T, const float* __restrict__ W2T,
    const float* __restrict__ s1, const float* __restrict__ t1,
    const float* __restrict__ s2, const float* __restrict__ t2,
    float* __restrict__ x1t)
{
  const int lane = threadIdx.x & 63;
  const int pt = (blockIdx.x << 2) + (threadIdx.x >> 6);
  const int b = pt >> 12, n = pt & 4095;
  const float* xb = x + (size_t)b*7*NN;
  float w1r[14], w2r[64];
  #pragma unroll
  for (int c=0;c<14;c++) w1r[c] = W1T[c*64 + lane];
  #pragma unroll
  for (int c=0;c<64;c++) w2r[c] = W2T[c*64 + lane];
  const float s1o=s1[lane], t1o=t1[lane], s2o=s2[lane], t2o=t2[lane];
  const float xq = (lane < 7) ? xb[lane*NN + n] : 0.f;
  const float xq0 = bc(xq,0), xq1 = bc(xq,1);
  float qy1 = 0.f;
  #pragma unroll
  for (int c=0;c<7;c++) qy1 += w1r[7+c]*bc(xq,c);
  const int* ip = idx + (size_t)pt*KK;
  float acc = 0.f;
  for (int j=0;j<KK;j++){
    const int ij = ip[j];
    const float xg = (lane < 7) ? xb[lane*NN + ij] : 0.f;
    float y1 = qy1;
    y1 += w1r[0]*(bc(xg,0) - xq0);
    y1 += w1r[1]*(bc(xg,1) - xq1);
    #pragma unroll
    for (int c=2;c<7;c++) y1 += w1r[c]*bc(xg,c);
    const float z1 = lrelu(y1*s1o + t1o);
    float p0=0.f,p1=0.f,p2=0.f,p3=0.f;
    #pragma unroll
    for (int c=0;c<64;c+=4){
      p0 += w2r[c+0]*bc(z1,c+0);
      p1 += w2r[c+1]*bc(z1,c+1);
      p2 += w2r[c+2]*bc(z1,c+2);
      p3 += w2r[c+3]*bc(z1,c+3);
    }
    acc += lrelu(((p0+p1)+(p2+p3))*s2o + t2o);
  }
  x1t[(size_t)pt*64 + lane] = acc / 10.f;
}

// ---------------- edge conv 2: graph_feature + W3 + W4 + mean ----------------
__global__ __launch_bounds__(256) void edge2_k(const float* __restrict__ xin, const int* __restrict__ idx,
    const float* __restrict__ W3T, const float* __restrict__ W4T,
    const float* __restrict__ s3, const float* __restrict__ t3,
    const float* __restrict__ s4, const float* __restrict__ t4,
    float* __restrict__ xout)
{
  const int lane = threadIdx.x & 63;
  const int pt = (blockIdx.x << 2) + (threadIdx.x >> 6);
  const int b = pt >> 12;
  float wd[64], wq[64], w4[64];
  #pragma unroll
  for (int c=0;c<64;c++) wd[c] = W3T[c*64 + lane];
  #pragma unroll
  for (int c=0;c<64;c++) wq[c] = W3T[(64+c)*64 + lane];
  #pragma unroll
  for (int c=0;c<64;c++) w4[c] = W4T[c*64 + lane];
  const float s3o=s3[lane], t3o=t3[lane], s4o=s4[lane], t4o=t4[lane];
  const float xq = xin[(size_t)pt*64 + lane];
  float a0=0.f,a1=0.f,a2=0.f,a3=0.f;
  #pragma unroll
  for (int c=0;c<64;c+=4){
    a0 += wq[c+0]*bc(xq,c+0);
    a1 += wq[c+1]*bc(xq,c+1);
    a2 += wq[c+2]*bc(xq,c+2);
    a3 += wq[c+3]*bc(xq,c+3);
  }
  const float yq = (a0+a1)+(a2+a3);
  const int* ip = idx + (size_t)pt*KK;
  float acc = 0.f;
  for (int j=0;j<KK;j++){
    const int ij = ip[j];
    const float xg = xin[((size_t)(b*NN + ij))*64 + lane];
    const float d = xg - xq;
    float p0=0.f,p1=0.f,p2=0.f,p3=0.f;
    #pragma unroll
    for (int c=0;c<64;c+=4){
      p0 += wd[c+0]*bc(d,c+0);
      p1 += wd[c+1]*bc(d,c+1);
      p2 += wd[c+2]*bc(d,c+2);
      p3 += wd[c+3]*bc(d,c+3);
    }
    const float z3 = lrelu((yq + ((p0+p1)+(p2+p3)))*s3o + t3o);
    float q0=0.f,q1=0.f,q2=0.f,q3=0.f;
    #pragma unroll
    for (int c=0;c<64;c+=4){
      q0 += w4[c+0]*bc(z3,c+0);
      q1 += w4[c+1]*bc(z3,c+1);
      q2 += w4[c+2]*bc(z3,c+2);
      q3 += w4[c+3]*bc(z3,c+3);
    }
    acc += lrelu(((q0+q1)+(q2+q3))*s4o + t4o);
  }
  xout[(size_t)pt*64 + lane] = acc / 10.f;
}

// ---------------- edge conv 3: graph_feature + W5 + mean ----------------
__global__ __launch_bounds__(256) void edge3_k(const float* __restrict__ xin, const int* __restrict__ idx,
    const float* __restrict__ W5T,
    const float* __restrict__ s5, const float* __restrict__ t5,
    float* __restrict__ xout)
{
  const int lane = threadIdx.x & 63;
  const int pt = (blockIdx.x << 2) + (threadIdx.x >> 6);
  const int b = pt >> 12;
  float wd[64], wq[64];
  #pragma unroll
  for (int c=0;c<64;c++) wd[c] = W5T[c*64 + lane];
  #pragma unroll
  for (int c=0;c<64;c++) wq[c] = W5T[(64+c)*64 + lane];
  const float s5o=s5[lane], t5o=t5[lane];
  const float xq = xin[(size_t)pt*64 + lane];
  float a0=0.f,a1=0.f,a2=0.f,a3=0.f;
  #pragma unroll
  for (int c=0;c<64;c+=4){
    a0 += wq[c+0]*bc(xq,c+0);
    a1 += wq[c+1]*bc(xq,c+1);
    a2 += wq[c+2]*bc(xq,c+2);
    a3 += wq[c+3]*bc(xq,c+3);
  }
  const float yq = (a0+a1)+(a2+a3);
  const int* ip = idx + (size_t)pt*KK;
  float acc = 0.f;
  for (int j=0;j<KK;j++){
    const int ij = ip[j];
    const float xg = xin[((size_t)(b*NN + ij))*64 + lane];
    const float d = xg - xq;
    float p0=0.f,p1=0.f,p2=0.f,p3=0.f;
    #pragma unroll
    for (int c=0;c<64;c+=4){
      p0 += wd[c+0]*bc(d,c+0);
      p1 += wd[c+1]*bc(d,c+1);
      p2 += wd[c+2]*bc(d,c+2);
      p3 += wd[c+3]*bc(d,c+3);
    }
    acc += lrelu((yq + ((p0+p1)+(p2+p3)))*s5o + t5o);
  }
  xout[(size_t)pt*64 + lane] = acc / 10.f;
}

// ---------------- G1: h6 = lrelu(W6@z), accumulate sum over N ----------------
__global__ __launch_bounds__(256) void g1_k(const float* __restrict__ W6,
   const float* __restrict__ x1t, const float* __restrict__ x2t, const float* __restrict__ x3t,
   const float* __restrict__ s6, const float* __restrict__ t6, float* __restrict__ gsum)
{
  __shared__ float Wl[16*132];
  __shared__ float Zl[16*260];
  const int tid = threadIdx.x;
  const int rb = blockIdx.x & 1;
  const int nt = (blockIdx.x >> 1) & 15;
  const int b  = blockIdx.x >> 5;
  const int r0 = rb*128;
  const int n0 = nt*256;
  const int ty = tid >> 4, tx = tid & 15;
  float acc[8][16];
  #pragma unroll
  for (int i=0;i<8;i++){
    #pragma unroll
    for (int j=0;j<16;j++) acc[i][j] = 0.f;
  }
  for (int kc=0; kc<12; kc++){
    __syncthreads();
    {
      const int r = tid >> 1, h = tid & 1;
      const float4* wp = (const float4*)(W6 + (size_t)(r0 + r)*192 + kc*16 + h*8);
      float tmp[8];
      *(float4*)&tmp[0] = wp[0];
      *(float4*)&tmp[4] = wp[1];
      #pragma unroll
      for (int u=0;u<8;u++) Wl[(h*8+u)*132 + r] = tmp[u];
    }
    {
      const float* arr = (kc < 4) ? x1t : (kc < 8) ? x2t : x3t;
      const int chofs = (kc & 3)*16;
      const float4* zp = (const float4*)(arr + ((size_t)(b*NN) + n0 + tid)*64 + chofs);
      float tmp[16];
      *(float4*)&tmp[0]  = zp[0];
      *(float4*)&tmp[4]  = zp[1];
      *(float4*)&tmp[8]  = zp[2];
      *(float4*)&tmp[12] = zp[3];
      #pragma unroll
      for (int u=0;u<16;u++) Zl[u*260 + tid] = tmp[u];
    }
    __syncthreads();
    #pragma unroll 4
    for (int k=0;k<16;k++){
      float wv[8], zv[16];
      *(float4*)&wv[0] = *(const float4*)(&Wl[k*132 + ty*8]);
      *(float4*)&wv[4] = *(const float4*)(&Wl[k*132 + ty*8 + 4]);
      #pragma unroll
      for (int jg=0;jg<4;jg++)
        *(float4*)&zv[jg*4] = *(const float4*)(&Zl[k*260 + jg*64 + tx*4]);
      #pragma unroll
      for (int i=0;i<8;i++){
        #pragma unroll
        for (int j=0;j<16;j++) acc[i][j] += wv[i]*zv[j];
      }
    }
  }
  #pragma unroll
  for (int i=0;i<8;i++){
    const int row = r0 + ty*8 + i;
    const float sv = s6[row], tv = t6[row];
    float sum = 0.f;
    #pragma unroll
    for (int j=0;j<16;j++) sum += lrelu(acc[i][j]*sv + tv);
    #pragma unroll
    for (int d=1; d<16; d<<=1) sum += __shfl_xor(sum, d, 64);
    if ((tid & 15) == 0) atomicAdd(&gsum[b*256 + row], sum);
  }
}

// ---------------- G2: c7 = W7[:, :256] @ (gsum/4096) ----------------
__global__ __launch_bounds__(256) void g2_k(const float* __restrict__ W7,
   const float* __restrict__ gsum, float* __restrict__ c7)
{
  const int b = blockIdx.x >> 1;
  const int o = (blockIdx.x & 1)*256 + threadIdx.x;
  const float* wr = W7 + (size_t)o*448;
  const float* gb = gsum + b*256;
  float a0=0.f,a1=0.f,a2=0.f,a3=0.f;
  #pragma unroll 4
  for (int c=0;c<256;c+=4){
    a0 += wr[c+0]*gb[c+0]; a1 += wr[c+1]*gb[c+1];
    a2 += wr[c+2]*gb[c+2]; a3 += wr[c+3]*gb[c+3];
  }
  c7[b*512+o] = ((a0+a1)+(a2+a3)) * (1.f/4096.f);
}

// ---------------- G3: h7 = lrelu((W7[:,256:]@z + c7)) -> max/sum over N ----------------
__global__ __launch_bounds__(256) void g3_k(const float* __restrict__ W7,
   const float* __restrict__ x1t, const float* __restrict__ x2t, const float* __restrict__ x3t,
   const float* __restrict__ c7, const float* __restrict__ s7, const float* __restrict__ t7,
   unsigned* __restrict__ x4e, float* __restrict__ x5s)
{
  __shared__ float Wl[16*132];
  __shared__ float Zl[16*260];
  const int tid = threadIdx.x;
  const int rb = blockIdx.x & 3;
  const int nt = (blockIdx.x >> 2) & 15;
  const int b  = blockIdx.x >> 6;
  const int r0 = rb*128;
  const int n0 = nt*256;
  const int ty = tid >> 4, tx = tid & 15;
  float acc[8][16];
  #pragma unroll
  for (int i=0;i<8;i++){
    #pragma unroll
    for (int j=0;j<16;j++) acc[i][j] = 0.f;
  }
  for (int kc=0; kc<12; kc++){
    __syncthreads();
    {
      const int r = tid >> 1, h = tid & 1;
      const float4* wp = (const float4*)(W7 + (size_t)(r0 + r)*448 + 256 + kc*16 + h*8);
      float tmp[8];
      *(float4*)&tmp[0] = wp[0];
      *(float4*)&tmp[4] = wp[1];
      #pragma unroll
      for (int u=0;u<8;u++) Wl[(h*8+u)*132 + r] = tmp[u];
    }
    {
      const float* arr = (kc < 4) ? x1t : (kc < 8) ? x2t : x3t;
      const int chofs = (kc & 3)*16;
      const float4* zp = (const float4*)(arr + ((size_t)(b*NN) + n0 + tid)*64 + chofs);
      float tmp[16];
      *(float4*)&tmp[0]  = zp[0];
      *(float4*)&tmp[4]  = zp[1];
      *(float4*)&tmp[8]  = zp[2];
      *(float4*)&tmp[12] = zp[3];
      #pragma unroll
      for (int u=0;u<16;u++) Zl[u*260 + tid] = tmp[u];
    }
    __syncthreads();
    #pragma unroll 4
    for (int k=0;k<16;k++){
      float wv[8], zv[16];
      *(float4*)&wv[0] = *(const float4*)(&Wl[k*132 + ty*8]);
      *(float4*)&wv[4] = *(const float4*)(&Wl[k*132 + ty*8 + 4]);
      #pragma unroll
      for (int jg=0;jg<4;jg++)
        *(float4*)&zv[jg*4] = *(const float4*)(&Zl[k*260 + jg*64 + tx*4]);
      #pragma unroll
      for (int i=0;i<8;i++){
        #pragma unroll
        for (int j=0;j<16;j++) acc[i][j] += wv[i]*zv[j];
      }
    }
  }
  #pragma unroll
  for (int i=0;i<8;i++){
    const int row = r0 + ty*8 + i;
    const float c7v = c7[b*512 + row];
    const float sv = s7[row], tv = t7[row];
    float mx = -__builtin_inff(), sum = 0.f;
    #pragma unroll
    for (int j=0;j<16;j++){
      float h = lrelu((acc[i][j] + c7v)*sv + tv);
      mx = fmaxf(mx, h); sum += h;
    }
    #pragma unroll
    for (int d=1; d<16; d<<=1){
      sum += __shfl_xor(sum, d, 64);
      mx = fmaxf(mx, __shfl_xor(mx, d, 64));
    }
    if ((tid & 15) == 0){
      atomicAdd(&x5s[b*512 + row], sum);
      atomicMax(&x4e[b*512 + row], fenc(mx));
    }
  }
}

// ---------------- G4: final linear ----------------
__global__ __launch_bounds__(128) void g4_k(const float* __restrict__ W8T,
  const unsigned* __restrict__ x4e, const float* __restrict__ x5s,
  const float* __restrict__ s8, const float* __restrict__ t8, float* __restrict__ out)
{
  const int b = blockIdx.x, j = threadIdx.x;
  float a0 = 0.f, a1 = 0.f;
  for (int o=0;o<512;o++){
    a0 += W8T[o*128 + j] * fdec(x4e[b*512 + o]);
    a1 += W8T[(512+o)*128 + j] * (x5s[b*512 + o] * (1.f/4096.f));
  }
  const float y = a0 + a1;
  out[b*128 + j] = lrelu(y*s8[j] + t8[j]);
}

extern "C" void kernel_launch(void* const* d_in, const int* in_sizes, int n_in,
                              void* d_out, int out_size, void* d_ws, size_t ws_size,
                              hipStream_t stream) {
  (void)in_sizes; (void)n_in; (void)out_size; (void)ws_size;
  const float* x  = (const float*)d_in[0];
  const float* W1 = (const float*)d_in[1];
  const float* W2 = (const float*)d_in[2];
  const float* W3 = (const float*)d_in[3];
  const float* W4 = (const float*)d_in[4];
  const float* W5 = (const float*)d_in[5];
  const float* W6 = (const float*)d_in[6];
  const float* W7 = (const float*)d_in[7];
  const float* W8 = (const float*)d_in[8];
  const float* s1 = (const float*)d_in[9];   const float* t1 = (const float*)d_in[10];
  const float* s2 = (const float*)d_in[11];  const float* t2 = (const float*)d_in[12];
  const float* s3 = (const float*)d_in[13];  const float* t3 = (const float*)d_in[14];
  const float* s4 = (const float*)d_in[15];  const float* t4 = (const float*)d_in[16];
  const float* s5 = (const float*)d_in[17];  const float* t5 = (const float*)d_in[18];
  const float* s6 = (const float*)d_in[19];  const float* t6 = (const float*)d_in[20];
  const float* s7 = (const float*)d_in[21];  const float* t7 = (const float*)d_in[22];
  const float* s8 = (const float*)d_in[23];  const float* t8 = (const float*)d_in[24];

  char* wsb = (char*)d_ws;
  size_t off = 0;
  auto alloc = [&](size_t bytes)->char* {
    char* p = wsb + off;
    off += (bytes + 255) & ~(size_t)255;
    return p;
  };
  int*      idx1 = (int*)alloc((size_t)BB*NN*KK*4);
  int*      idx2 = (int*)alloc((size_t)BB*NN*KK*4);
  int*      idx3 = (int*)alloc((size_t)BB*NN*KK*4);
  u64*      pkeys= (u64*)alloc((size_t)BB*NN*2*KK*8);
  float*    x1t  = (float*)alloc((size_t)BB*NN*64*4);
  float*    x2t  = (float*)alloc((size_t)BB*NN*64*4);
  float*    x3t  = (float*)alloc((size_t)BB*NN*64*4);
  float*    gsum = (float*)alloc((size_t)BB*256*4);
  unsigned* x4e  = (unsigned*)alloc((size_t)BB*512*4);
  float*    x5s  = (float*)alloc((size_t)BB*512*4);
  float*    c7   = (float*)alloc((size_t)BB*512*4);
  float*    W1T  = (float*)alloc(14*64*4);
  float*    W2T  = (float*)alloc(64*64*4);
  float*    W3T  = (float*)alloc(128*64*4);
  float*    W4T  = (float*)alloc(64*64*4);
  float*    W5T  = (float*)alloc(128*64*4);
  float*    W8T  = (float*)alloc(1024*128*4);

  prep_k<<<64,256,0,stream>>>(W1,W2,W3,W4,W5,W8, W1T,W2T,W3T,W4T,W5T,W8T);
  knn2d_k<<<BB*64*2,256,0,stream>>>(x, pkeys);
  kmerge_k<<<BB*NN/256,256,0,stream>>>(pkeys, idx1);
  edge1_k<<<BB*NN/4,256,0,stream>>>(x, idx1, W1T, W2T, s1,t1,s2,t2, x1t);
  knn64_k<<<BB*64*2,256,0,stream>>>(x1t, pkeys);
  kmerge_k<<<BB*NN/256,256,0,stream>>>(pkeys, idx2);
  edge2_k<<<BB*NN/4,256,0,stream>>>(x1t, idx2, W3T, W4T, s3,t3,s4,t4, x2t);
  knn64_k<<<BB*64*2,256,0,stream>>>(x2t, pkeys);
  kmerge_k<<<BB*NN/256,256,0,stream>>>(pkeys, idx3);
  edge3_k<<<BB*NN/4,256,0,stream>>>(x2t, idx3, W5T, s5,t5, x3t);
  hipMemsetAsync(gsum, 0, (size_t)BB*256*4 + (size_t)BB*512*4*2, stream);
  g1_k<<<256,256,0,stream>>>(W6, x1t,x2t,x3t, s6,t6, gsum);
  g2_k<<<16,256,0,stream>>>(W7, gsum, c7);
  g3_k<<<512,256,0,stream>>>(W7, x1t,x2t,x3t, c7, s7,t7, x4e, x5s);
  g4_k<<<BB,128,0,stream>>>(W8T, x4e, x5s, s8,t8, (float*)d_out);
}

// Round 8
// 1886.778 us; speedup vs baseline: 1.2369x; 1.2369x over previous
//
#include <hip/hip_runtime.h>

#define BB 8
#define NN 4096
#define KK 10
typedef unsigned long long u64;
typedef __attribute__((ext_vector_type(8))) short bf16x8;
typedef __attribute__((ext_vector_type(4))) float f32x4;

__device__ __forceinline__ float lrelu(float v){ return v >= 0.f ? v : 0.2f*v; }
__device__ __forceinline__ float bc(float v, int l){
  return __int_as_float(__builtin_amdgcn_readlane(__float_as_int(v), l));
}
__device__ __forceinline__ unsigned fenc(float f){
  unsigned u = __float_as_uint(f);
  return u ^ (((unsigned)((int)u >> 31)) | 0x80000000u);
}
__device__ __forceinline__ float fdec(unsigned e){
  return (e & 0x80000000u) ? __uint_as_float(e & 0x7fffffffu) : __uint_as_float(~e);
}
__device__ __forceinline__ u64 shflx_u64(u64 x, int d){
  unsigned lo = __shfl_xor((unsigned)x, d, 64);
  unsigned hi = __shfl_xor((unsigned)(x >> 32), d, 64);
  return ((u64)hi << 32) | lo;
}

// ---------------- weight transposes (one-time tiny prep) ----------------
__global__ __launch_bounds__(256) void prep_k(
    const float* __restrict__ W1, const float* __restrict__ W2, const float* __restrict__ W3,
    const float* __restrict__ W4, const float* __restrict__ W5, const float* __restrict__ W8,
    float* __restrict__ W1T, float* __restrict__ W2T, float* __restrict__ W3T,
    float* __restrict__ W4T, float* __restrict__ W5T, float* __restrict__ W8T)
{
  const int t = blockIdx.x*256 + threadIdx.x;
  const int stride = gridDim.x*256;
  for (int i=t; i<64*14; i+=stride){ int o=i/14, c=i%14; W1T[c*64+o]=W1[i]; }
  for (int i=t; i<64*64; i+=stride){ int o=i>>6, c=i&63; W2T[c*64+o]=W2[i]; }
  for (int i=t; i<64*128; i+=stride){ int o=i>>7, c=i&127; W3T[c*64+o]=W3[i]; }
  for (int i=t; i<64*64; i+=stride){ int o=i>>6, c=i&63; W4T[c*64+o]=W4[i]; }
  for (int i=t; i<64*128; i+=stride){ int o=i>>7, c=i&127; W5T[c*64+o]=W5[i]; }
  for (int i=t; i<128*1024; i+=stride){ int o=i>>10, c=i&1023; W8T[c*128+o]=W8[i]; }
}

// ---------------- knn over first 2 channels (candidate-split halves) ----------------
__global__ __launch_bounds__(256) void knn2d_k(const float* __restrict__ x, u64* __restrict__ pk)
{
  __shared__ float px[2048], py[2048], pxx[2048];
  const int tid = threadIdx.x;
  const int b  = blockIdx.x >> 7;
  const int qt = (blockIdx.x >> 1) & 63;
  const int h  = blockIdx.x & 1;
  const int q0 = qt*64;
  const int m0g = h*2048;
  const float* xb = x + (size_t)b*7*NN;
  for (int m = tid; m < 2048; m += 256){
    float a = xb[m0g + m], c = xb[NN + m0g + m];
    px[m] = a; py[m] = c; pxx[m] = a*a + c*c;
  }
  __syncthreads();

  const int ty = tid >> 4, tx = tid & 15;
  const int qr = ty*4;
  float qx4[4], qy4[4], q24[4];
  #pragma unroll
  for (int i=0;i<4;i++){
    float a = xb[q0+qr+i], c = xb[NN + q0+qr+i];
    qx4[i] = a; qy4[i] = c; q24[i] = a*a + c*c;
  }

  u64 bk[4][KK]; u64 tau[4];
  #pragma unroll
  for (int i=0;i<4;i++){
    tau[i] = 0ull;
    #pragma unroll
    for (int s=0;s<KK;s++) bk[i][s] = 0ull;
  }

  for (int ot=0; ot<16; ot++){
    #pragma unroll
    for (int j=0;j<8;j++){
      const int ml = ot*128 + j*16 + tx;
      const float cmx = px[ml], cmy = py[ml], cm2 = pxx[ml];
      const unsigned mk = ~(unsigned)(m0g + ml);
      #pragma unroll
      for (int i=0;i<4;i++){
        float dot = qx4[i]*cmx + qy4[i]*cmy;
        float v = (-q24[i]) - (-2.f*dot) - cm2;
        u64 key = ((u64)fenc(v) << 32) | mk;
        if (key >= tau[i]){
          if (key > bk[i][KK-1]){
            bk[i][KK-1] = key;
            #pragma unroll
            for (int s=KK-1;s>0;s--){
              if (bk[i][s] > bk[i][s-1]){ u64 t=bk[i][s]; bk[i][s]=bk[i][s-1]; bk[i][s-1]=t; }
            }
          }
        }
      }
    }
    #pragma unroll
    for (int i=0;i<4;i++){
      u64 t = bk[i][KK-1];
      t = t > shflx_u64(t,1) ? t : shflx_u64(t,1);
      t = t > shflx_u64(t,2) ? t : shflx_u64(t,2);
      t = t > shflx_u64(t,4) ? t : shflx_u64(t,4);
      t = t > shflx_u64(t,8) ? t : shflx_u64(t,8);
      tau[i] = t;
    }
  }

  #pragma unroll
  for (int i=0;i<4;i++){
    #pragma unroll
    for (int k=0;k<KK;k++){
      u64 best = bk[i][0];
      #pragma unroll
      for (int d=1; d<16; d<<=1){
        u64 o = shflx_u64(best, d);
        if (o > best) best = o;
      }
      if (bk[i][0] == best){
        #pragma unroll
        for (int s=0;s<KK-1;s++) bk[i][s] = bk[i][s+1];
        bk[i][KK-1] = 0ull;
      }
      if (tx == 0) pk[(((size_t)b*NN + q0 + qr + i)*2 + h)*KK + k] = best;
    }
  }
}

// ---------------- knn over 64 channels: split-bf16 MFMA distances ----------------
// Distances via mfma_f32_16x16x32_bf16 with hi/lo split (x = hi + lo, truncated bf16):
// dot = Ah.Bh + Ah.Bl + Al.Bh  (~2^-16 rel error). C/D layout (m89-verified):
// col=lane&15 -> candidate, row=quad*4+reg -> query. Each lane owns 4q x 4c per
// 64-cand tile -> identical selection footprint to the fp32 version; u64 key/tau/
// ladder/merge logic unchanged. LDS per block ~37.4KB -> 4 blocks/CU.
__global__ __launch_bounds__(256) void knn64_k(const float* __restrict__ xt, u64* __restrict__ pk)
{
  __shared__ unsigned short Qh[64*72], Ql[64*72];   // 9216 B each (72-ch padded rows)
  __shared__ unsigned short Ch[64*72], Cl[64*72];
  __shared__ float qxx[64], cxx[64];
  const int tid = threadIdx.x;
  const int b  = blockIdx.x >> 7;
  const int qt = (blockIdx.x >> 1) & 63;
  const int h  = blockIdx.x & 1;
  const int q0 = qt*64;
  const int m0g = h*2048;
  const float* xb = xt + (size_t)b*NN*64;

  const int sp = tid >> 2;          // staging point 0..63
  const int sc = (tid & 3) << 4;    // staging channel base 0,16,32,48

  // ---- stage Q tile (hi/lo bf16) + qxx ----
  {
    const float* src = xb + (size_t)(q0+sp)*64 + sc;
    float ssq = 0.f;
    #pragma unroll
    for (int g=0; g<2; g++){
      float fv[8];
      *(float4*)&fv[0] = *(const float4*)(src + g*8);
      *(float4*)&fv[4] = *(const float4*)(src + g*8 + 4);
      unsigned hp[4], lp[4];
      #pragma unroll
      for (int e=0; e<4; e++){
        float f0 = fv[2*e], f1 = fv[2*e+1];
        ssq += f0*f0 + f1*f1;
        unsigned u0 = __float_as_uint(f0), u1 = __float_as_uint(f1);
        hp[e] = (u0 >> 16) | (u1 & 0xffff0000u);
        float l0 = f0 - __uint_as_float(u0 & 0xffff0000u);
        float l1 = f1 - __uint_as_float(u1 & 0xffff0000u);
        lp[e] = (__float_as_uint(l0) >> 16) | (__float_as_uint(l1) & 0xffff0000u);
      }
      *(uint4*)(&Qh[sp*72 + sc + g*8]) = uint4{hp[0],hp[1],hp[2],hp[3]};
      *(uint4*)(&Ql[sp*72 + sc + g*8]) = uint4{lp[0],lp[1],lp[2],lp[3]};
    }
    ssq += __shfl_xor(ssq, 1, 64);
    ssq += __shfl_xor(ssq, 2, 64);
    if ((tid & 3) == 0) qxx[sp] = ssq;
  }
  __syncthreads();

  const int lane = tid & 63;
  const int w    = tid >> 6;
  const int col  = lane & 15;
  const int quad = (tid >> 4) & 3;
  const int qr   = (tid >> 4)*4;              // == w*16 + quad*4 (selection query base)
  const int aoff = (w*16 + col)*72 + quad*8;  // A-frag ushort index (kc adds +32)

  float qx4[4];
  #pragma unroll
  for (int i=0;i<4;i++) qx4[i] = qxx[qr+i];

  u64 bk[4][KK]; u64 tau[4];
  #pragma unroll
  for (int i=0;i<4;i++){
    tau[i] = 0ull;
    #pragma unroll
    for (int s=0;s<KK;s++) bk[i][s] = 0ull;
  }

  for (int ct=0; ct<32; ct++){
    const int m0 = m0g + ct*64;
    __syncthreads();
    // ---- stage C tile (hi/lo bf16) + cxx ----
    {
      const float* src = xb + (size_t)(m0+sp)*64 + sc;
      float ssq = 0.f;
      #pragma unroll
      for (int g=0; g<2; g++){
        float fv[8];
        *(float4*)&fv[0] = *(const float4*)(src + g*8);
        *(float4*)&fv[4] = *(const float4*)(src + g*8 + 4);
        unsigned hp[4], lp[4];
        #pragma unroll
        for (int e=0; e<4; e++){
          float f0 = fv[2*e], f1 = fv[2*e+1];
          ssq += f0*f0 + f1*f1;
          unsigned u0 = __float_as_uint(f0), u1 = __float_as_uint(f1);
          hp[e] = (u0 >> 16) | (u1 & 0xffff0000u);
          float l0 = f0 - __uint_as_float(u0 & 0xffff0000u);
          float l1 = f1 - __uint_as_float(u1 & 0xffff0000u);
          lp[e] = (__float_as_uint(l0) >> 16) | (__float_as_uint(l1) & 0xffff0000u);
        }
        *(uint4*)(&Ch[sp*72 + sc + g*8]) = uint4{hp[0],hp[1],hp[2],hp[3]};
        *(uint4*)(&Cl[sp*72 + sc + g*8]) = uint4{lp[0],lp[1],lp[2],lp[3]};
      }
      ssq += __shfl_xor(ssq, 1, 64);
      ssq += __shfl_xor(ssq, 2, 64);
      if ((tid & 3) == 0) cxx[sp] = ssq;
    }
    __syncthreads();

    bf16x8 Ah0 = *(const bf16x8*)(&Qh[aoff]);
    bf16x8 Ah1 = *(const bf16x8*)(&Qh[aoff+32]);
    bf16x8 Al0 = *(const bf16x8*)(&Ql[aoff]);
    bf16x8 Al1 = *(const bf16x8*)(&Ql[aoff+32]);

    #pragma unroll
    for (int j=0;j<4;j++){
      const int boff = (j*16 + col)*72 + quad*8;
      bf16x8 Bh0 = *(const bf16x8*)(&Ch[boff]);
      bf16x8 Bh1 = *(const bf16x8*)(&Ch[boff+32]);
      bf16x8 Bl0 = *(const bf16x8*)(&Cl[boff]);
      bf16x8 Bl1 = *(const bf16x8*)(&Cl[boff+32]);
      f32x4 d = {0.f,0.f,0.f,0.f};
      d = __builtin_amdgcn_mfma_f32_16x16x32_bf16(Al0, Bh0, d, 0,0,0);
      d = __builtin_amdgcn_mfma_f32_16x16x32_bf16(Ah0, Bl0, d, 0,0,0);
      d = __builtin_amdgcn_mfma_f32_16x16x32_bf16(Ah0, Bh0, d, 0,0,0);
      d = __builtin_amdgcn_mfma_f32_16x16x32_bf16(Al1, Bh1, d, 0,0,0);
      d = __builtin_amdgcn_mfma_f32_16x16x32_bf16(Ah1, Bl1, d, 0,0,0);
      d = __builtin_amdgcn_mfma_f32_16x16x32_bf16(Ah1, Bh1, d, 0,0,0);

      const int m = m0 + j*16 + col;
      const float cx = cxx[j*16 + col];
      const unsigned mk = ~(unsigned)m;
      #pragma unroll
      for (int i=0;i<4;i++){
        float v = (-qx4[i]) - (-2.f*d[i]) - cx;
        u64 key = ((u64)fenc(v) << 32) | mk;
        if (key >= tau[i]){
          if (key > bk[i][KK-1]){
            bk[i][KK-1] = key;
            #pragma unroll
            for (int s=KK-1;s>0;s--){
              if (bk[i][s] > bk[i][s-1]){ u64 t=bk[i][s]; bk[i][s]=bk[i][s-1]; bk[i][s-1]=t; }
            }
          }
        }
      }
    }
    #pragma unroll
    for (int i=0;i<4;i++){
      u64 t = bk[i][KK-1];
      t = t > shflx_u64(t,1) ? t : shflx_u64(t,1);
      t = t > shflx_u64(t,2) ? t : shflx_u64(t,2);
      t = t > shflx_u64(t,4) ? t : shflx_u64(t,4);
      t = t > shflx_u64(t,8) ? t : shflx_u64(t,8);
      tau[i] = t;
    }
  }

  #pragma unroll
  for (int i=0;i<4;i++){
    #pragma unroll
    for (int k=0;k<KK;k++){
      u64 best = bk[i][0];
      #pragma unroll
      for (int d=1; d<16; d<<=1){
        u64 o = shflx_u64(best, d);
        if (o > best) best = o;
      }
      if (bk[i][0] == best){
        #pragma unroll
        for (int s=0;s<KK-1;s++) bk[i][s] = bk[i][s+1];
        bk[i][KK-1] = 0ull;
      }
      if ((tid & 15) == 0) pk[(((size_t)b*NN + q0 + qr + i)*2 + h)*KK + k] = best;
    }
  }
}

// ---------------- merge two sorted-desc 10-key halves -> final idx ----------------
__global__ __launch_bounds__(256) void kmerge_k(const u64* __restrict__ pk, int* __restrict__ idxo)
{
  const int q = blockIdx.x*256 + threadIdx.x;   // q < BB*NN
  const u64* A = pk + (size_t)q*(2*KK);
  int* op = idxo + (size_t)q*KK;
  int ia = 0, ib = 0;
  #pragma unroll
  for (int k=0;k<KK;k++){
    u64 a = (ia < KK) ? A[ia] : 0ull;
    u64 b2 = (ib < KK) ? A[KK+ib] : 0ull;
    if (a >= b2){ op[k] = (int)(~(unsigned)a); ia++; }
    else        { op[k] = (int)(~(unsigned)b2); ib++; }
  }
}

// ---------------- edge conv 1: graph_feature1 + W1 + W2 + mean ----------------
__global__ __launch_bounds__(256) void edge1_k(const float* __restrict__ x, const int* __restrict__ idx,
    const float* __restrict__ W1T, const float* __restrict__ W2T,
    const float* __restrict__ s1, const float* __restrict__ t1,
    const float* __restrict__ s2, const float* __restrict__ t2,
    float* __restrict__ x1t)
{
  const int lane = threadIdx.x & 63;
  const int pt = (blockIdx.x << 2) + (threadIdx.x >> 6);
  const int b = pt >> 12, n = pt & 4095;
  const float* xb = x + (size_t)b*7*NN;
  float w1r[14], w2r[64];
  #pragma unroll
  for (int c=0;c<14;c++) w1r[c] = W1T[c*64 + lane];
  #pragma unroll
  for (int c=0;c<64;c++) w2r[c] = W2T[c*64 + lane];
  const float s1o=s1[lane], t1o=t1[lane], s2o=s2[lane], t2o=t2[lane];
  const float xq = (lane < 7) ? xb[lane*NN + n] : 0.f;
  const float xq0 = bc(xq,0), xq1 = bc(xq,1);
  float qy1 = 0.f;
  #pragma unroll
  for (int c=0;c<7;c++) qy1 += w1r[7+c]*bc(xq,c);
  const int* ip = idx + (size_t)pt*KK;
  float acc = 0.f;
  for (int j=0;j<KK;j++){
    const int ij = ip[j];
    const float xg = (lane < 7) ? xb[lane*NN + ij] : 0.f;
    float y1 = qy1;
    y1 += w1r[0]*(bc(xg,0) - xq0);
    y1 += w1r[1]*(bc(xg,1) - xq1);
    #pragma unroll
    for (int c=2;c<7;c++) y1 += w1r[c]*bc(xg,c);
    const float z1 = lrelu(y1*s1o + t1o);
    float p0=0.f,p1=0.f,p2=0.f,p3=0.f;
    #pragma unroll
    for (int c=0;c<64;c+=4){
      p0 += w2r[c+0]*bc(z1,c+0);
      p1 += w2r[c+1]*bc(z1,c+1);
      p2 += w2r[c+2]*bc(z1,c+2);
      p3 += w2r[c+3]*bc(z1,c+3);
    }
    acc += lrelu(((p0+p1)+(p2+p3))*s2o + t2o);
  }
  x1t[(size_t)pt*64 + lane] = acc / 10.f;
}

// ---------------- edge conv 2: graph_feature + W3 + W4 + mean ----------------
__global__ __launch_bounds__(256) void edge2_k(const float* __restrict__ xin, const int* __restrict__ idx,
    const float* __restrict__ W3T, const float* __restrict__ W4T,
    const float* __restrict__ s3, const float* __restrict__ t3,
    const float* __restrict__ s4, const float* __restrict__ t4,
    float* __restrict__ xout)
{
  const int lane = threadIdx.x & 63;
  const int pt = (blockIdx.x << 2) + (threadIdx.x >> 6);
  const int b = pt >> 12;
  float wd[64], wq[64], w4[64];
  #pragma unroll
  for (int c=0;c<64;c++) wd[c] = W3T[c*64 + lane];
  #pragma unroll
  for (int c=0;c<64;c++) wq[c] = W3T[(64+c)*64 + lane];
  #pragma unroll
  for (int c=0;c<64;c++) w4[c] = W4T[c*64 + lane];
  const float s3o=s3[lane], t3o=t3[lane], s4o=s4[lane], t4o=t4[lane];
  const float xq = xin[(size_t)pt*64 + lane];
  float a0=0.f,a1=0.f,a2=0.f,a3=0.f;
  #pragma unroll
  for (int c=0;c<64;c+=4){
    a0 += wq[c+0]*bc(xq,c+0);
    a1 += wq[c+1]*bc(xq,c+1);
    a2 += wq[c+2]*bc(xq,c+2);
    a3 += wq[c+3]*bc(xq,c+3);
  }
  const float yq = (a0+a1)+(a2+a3);
  const int* ip = idx + (size_t)pt*KK;
  float acc = 0.f;
  for (int j=0;j<KK;j++){
    const int ij = ip[j];
    const float xg = xin[((size_t)(b*NN + ij))*64 + lane];
    const float d = xg - xq;
    float p0=0.f,p1=0.f,p2=0.f,p3=0.f;
    #pragma unroll
    for (int c=0;c<64;c+=4){
      p0 += wd[c+0]*bc(d,c+0);
      p1 += wd[c+1]*bc(d,c+1);
      p2 += wd[c+2]*bc(d,c+2);
      p3 += wd[c+3]*bc(d,c+3);
    }
    const float z3 = lrelu((yq + ((p0+p1)+(p2+p3)))*s3o + t3o);
    float q0=0.f,q1=0.f,q2=0.f,q3=0.f;
    #pragma unroll
    for (int c=0;c<64;c+=4){
      q0 += w4[c+0]*bc(z3,c+0);
      q1 += w4[c+1]*bc(z3,c+1);
      q2 += w4[c+2]*bc(z3,c+2);
      q3 += w4[c+3]*bc(z3,c+3);
    }
    acc += lrelu(((q0+q1)+(q2+q3))*s4o + t4o);
  }
  xout[(size_t)pt*64 + lane] = acc / 10.f;
}

// ---------------- edge conv 3: graph_feature + W5 + mean ----------------
__global__ __launch_bounds__(256) void edge3_k(const float* __restrict__ xin, const int* __restrict__ idx,
    const float* __restrict__ W5T,
    const float* __restrict__ s5, const float* __restrict__ t5,
    float* __restrict__ xout)
{
  const int lane = threadIdx.x & 63;
  const int pt = (blockIdx.x << 2) + (threadIdx.x >> 6);
  const int b = pt >> 12;
  float wd[64], wq[64];
  #pragma unroll
  for (int c=0;c<64;c++) wd[c] = W5T[c*64 + lane];
  #pragma unroll
  for (int c=0;c<64;c++) wq[c] = W5T[(64+c)*64 + lane];
  const float s5o=s5[lane], t5o=t5[lane];
  const float xq = xin[(size_t)pt*64 + lane];
  float a0=0.f,a1=0.f,a2=0.f,a3=0.f;
  #pragma unroll
  for (int c=0;c<64;c+=4){
    a0 += wq[c+0]*bc(xq,c+0);
    a1 += wq[c+1]*bc(xq,c+1);
    a2 += wq[c+2]*bc(xq,c+2);
    a3 += wq[c+3]*bc(xq,c+3);
  }
  const float yq = (a0+a1)+(a2+a3);
  const int* ip = idx + (size_t)pt*KK;
  float acc = 0.f;
  for (int j=0;j<KK;j++){
    const int ij = ip[j];
    const float xg = xin[((size_t)(b*NN + ij))*64 + lane];
    const float d = xg - xq;
    float p0=0.f,p1=0.f,p2=0.f,p3=0.f;
    #pragma unroll
    for (int c=0;c<64;c+=4){
      p0 += wd[c+0]*bc(d,c+0);
      p1 += wd[c+1]*bc(d,c+1);
      p2 += wd[c+2]*bc(d,c+2);
      p3 += wd[c+3]*bc(d,c+3);
    }
    acc += lrelu((yq + ((p0+p1)+(p2+p3)))*s5o + t5o);
  }
  xout[(size_t)pt*64 + lane] = acc / 10.f;
}

// ---------------- G1: h6 = lrelu(W6@z), accumulate sum over N ----------------
__global__ __launch_bounds__(256) void g1_k(const float* __restrict__ W6,
   const float* __restrict__ x1t, const float* __restrict__ x2t, const float* __restrict__ x3t,
   const float* __restrict__ s6, const float* __restrict__ t6, float* __restrict__ gsum)
{
  __shared__ float Wl[16*132];
  __shared__ float Zl[16*260];
  const int tid = threadIdx.x;
  const int rb = blockIdx.x & 1;
  const int nt = (blockIdx.x >> 1) & 15;
  const int b  = blockIdx.x >> 5;
  const int r0 = rb*128;
  const int n0 = nt*256;
  const int ty = tid >> 4, tx = tid & 15;
  float acc[8][16];
  #pragma unroll
  for (int i=0;i<8;i++){
    #pragma unroll
    for (int j=0;j<16;j++) acc[i][j] = 0.f;
  }
  for (int kc=0; kc<12; kc++){
    __syncthreads();
    {
      const int r = tid >> 1, h = tid & 1;
      const float4* wp = (const float4*)(W6 + (size_t)(r0 + r)*192 + kc*16 + h*8);
      float tmp[8];
      *(float4*)&tmp[0] = wp[0];
      *(float4*)&tmp[4] = wp[1];
      #pragma unroll
      for (int u=0;u<8;u++) Wl[(h*8+u)*132 + r] = tmp[u];
    }
    {
      const float* arr = (kc < 4) ? x1t : (kc < 8) ? x2t : x3t;
      const int chofs = (kc & 3)*16;
      const float4* zp = (const float4*)(arr + ((size_t)(b*NN) + n0 + tid)*64 + chofs);
      float tmp[16];
      *(float4*)&tmp[0]  = zp[0];
      *(float4*)&tmp[4]  = zp[1];
      *(float4*)&tmp[8]  = zp[2];
      *(float4*)&tmp[12] = zp[3];
      #pragma unroll
      for (int u=0;u<16;u++) Zl[u*260 + tid] = tmp[u];
    }
    __syncthreads();
    #pragma unroll 4
    for (int k=0;k<16;k++){
      float wv[8], zv[16];
      *(float4*)&wv[0] = *(const float4*)(&Wl[k*132 + ty*8]);
      *(float4*)&wv[4] = *(const float4*)(&Wl[k*132 + ty*8 + 4]);
      #pragma unroll
      for (int jg=0;jg<4;jg++)
        *(float4*)&zv[jg*4] = *(const float4*)(&Zl[k*260 + jg*64 + tx*4]);
      #pragma unroll
      for (int i=0;i<8;i++){
        #pragma unroll
        for (int j=0;j<16;j++) acc[i][j] += wv[i]*zv[j];
      }
    }
  }
  #pragma unroll
  for (int i=0;i<8;i++){
    const int row = r0 + ty*8 + i;
    const float sv = s6[row], tv = t6[row];
    float sum = 0.f;
    #pragma unroll
    for (int j=0;j<16;j++) sum += lrelu(acc[i][j]*sv + tv);
    #pragma unroll
    for (int d=1; d<16; d<<=1) sum += __shfl_xor(sum, d, 64);
    if ((tid & 15) == 0) atomicAdd(&gsum[b*256 + row], sum);
  }
}

// ---------------- G2: c7 = W7[:, :256] @ (gsum/4096) ----------------
__global__ __launch_bounds__(256) void g2_k(const float* __restrict__ W7,
   const float* __restrict__ gsum, float* __restrict__ c7)
{
  const int b = blockIdx.x >> 1;
  const int o = (blockIdx.x & 1)*256 + threadIdx.x;
  const float* wr = W7 + (size_t)o*448;
  const float* gb = gsum + b*256;
  float a0=0.f,a1=0.f,a2=0.f,a3=0.f;
  #pragma unroll 4
  for (int c=0;c<256;c+=4){
    a0 += wr[c+0]*gb[c+0]; a1 += wr[c+1]*gb[c+1];
    a2 += wr[c+2]*gb[c+2]; a3 += wr[c+3]*gb[c+3];
  }
  c7[b*512+o] = ((a0+a1)+(a2+a3)) * (1.f/4096.f);
}

// ---------------- G3: h7 = lrelu((W7[:,256:]@z + c7)) -> max/sum over N ----------------
__global__ __launch_bounds__(256) void g3_k(const float* __restrict__ W7,
   const float* __restrict__ x1t, const float* __restrict__ x2t, const float* __restrict__ x3t,
   const float* __restrict__ c7, const float* __restrict__ s7, const float* __restrict__ t7,
   unsigned* __restrict__ x4e, float* __restrict__ x5s)
{
  __shared__ float Wl[16*132];
  __shared__ float Zl[16*260];
  const int tid = threadIdx.x;
  const int rb = blockIdx.x & 3;
  const int nt = (blockIdx.x >> 2) & 15;
  const int b  = blockIdx.x >> 6;
  const int r0 = rb*128;
  const int n0 = nt*256;
  const int ty = tid >> 4, tx = tid & 15;
  float acc[8][16];
  #pragma unroll
  for (int i=0;i<8;i++){
    #pragma unroll
    for (int j=0;j<16;j++) acc[i][j] = 0.f;
  }
  for (int kc=0; kc<12; kc++){
    __syncthreads();
    {
      const int r = tid >> 1, h = tid & 1;
      const float4* wp = (const float4*)(W7 + (size_t)(r0 + r)*448 + 256 + kc*16 + h*8);
      float tmp[8];
      *(float4*)&tmp[0] = wp[0];
      *(float4*)&tmp[4] = wp[1];
      #pragma unroll
      for (int u=0;u<8;u++) Wl[(h*8+u)*132 + r] = tmp[u];
    }
    {
      const float* arr = (kc < 4) ? x1t : (kc < 8) ? x2t : x3t;
      const int chofs = (kc & 3)*16;
      const float4* zp = (const float4*)(arr + ((size_t)(b*NN) + n0 + tid)*64 + chofs);
      float tmp[16];
      *(float4*)&tmp[0]  = zp[0];
      *(float4*)&tmp[4]  = zp[1];
      *(float4*)&tmp[8]  = zp[2];
      *(float4*)&tmp[12] = zp[3];
      #pragma unroll
      for (int u=0;u<16;u++) Zl[u*260 + tid] = tmp[u];
    }
    __syncthreads();
    #pragma unroll 4
    for (int k=0;k<16;k++){
      float wv[8], zv[16];
      *(float4*)&wv[0] = *(const float4*)(&Wl[k*132 + ty*8]);
      *(float4*)&wv[4] = *(const float4*)(&Wl[k*132 + ty*8 + 4]);
      #pragma unroll
      for (int jg=0;jg<4;jg++)
        *(float4*)&zv[jg*4] = *(const float4*)(&Zl[k*260 + jg*64 + tx*4]);
      #pragma unroll
      for (int i=0;i<8;i++){
        #pragma unroll
        for (int j=0;j<16;j++) acc[i][j] += wv[i]*zv[j];
      }
    }
  }
  #pragma unroll
  for (int i=0;i<8;i++){
    const int row = r0 + ty*8 + i;
    const float c7v = c7[b*512 + row];
    const float sv = s7[row], tv = t7[row];
    float mx = -__builtin_inff(), sum = 0.f;
    #pragma unroll
    for (int j=0;j<16;j++){
      float h = lrelu((acc[i][j] + c7v)*sv + tv);
      mx = fmaxf(mx, h); sum += h;
    }
    #pragma unroll
    for (int d=1; d<16; d<<=1){
      sum += __shfl_xor(sum, d, 64);
      mx = fmaxf(mx, __shfl_xor(mx, d, 64));
    }
    if ((tid & 15) == 0){
      atomicAdd(&x5s[b*512 + row], sum);
      atomicMax(&x4e[b*512 + row], fenc(mx));
    }
  }
}

// ---------------- G4: final linear ----------------
__global__ __launch_bounds__(128) void g4_k(const float* __restrict__ W8T,
  const unsigned* __restrict__ x4e, const float* __restrict__ x5s,
  const float* __restrict__ s8, const float* __restrict__ t8, float* __restrict__ out)
{
  const int b = blockIdx.x, j = threadIdx.x;
  float a0 = 0.f, a1 = 0.f;
  for (int o=0;o<512;o++){
    a0 += W8T[o*128 + j] * fdec(x4e[b*512 + o]);
    a1 += W8T[(512+o)*128 + j] * (x5s[b*512 + o] * (1.f/4096.f));
  }
  const float y = a0 + a1;
  out[b*128 + j] = lrelu(y*s8[j] + t8[j]);
}

extern "C" void kernel_launch(void* const* d_in, const int* in_sizes, int n_in,
                              void* d_out, int out_size, void* d_ws, size_t ws_size,
                              hipStream_t stream) {
  (void)in_sizes; (void)n_in; (void)out_size; (void)ws_size;
  const float* x  = (const float*)d_in[0];
  const float* W1 = (const float*)d_in[1];
  const float* W2 = (const float*)d_in[2];
  const float* W3 = (const float*)d_in[3];
  const float* W4 = (const float*)d_in[4];
  const float* W5 = (const float*)d_in[5];
  const float* W6 = (const float*)d_in[6];
  const float* W7 = (const float*)d_in[7];
  const float* W8 = (const float*)d_in[8];
  const float* s1 = (const float*)d_in[9];   const float* t1 = (const float*)d_in[10];
  const float* s2 = (const float*)d_in[11];  const float* t2 = (const float*)d_in[12];
  const float* s3 = (const float*)d_in[13];  const float* t3 = (const float*)d_in[14];
  const float* s4 = (const float*)d_in[15];  const float* t4 = (const float*)d_in[16];
  const float* s5 = (const float*)d_in[17];  const float* t5 = (const float*)d_in[18];
  const float* s6 = (const float*)d_in[19];  const float* t6 = (const float*)d_in[20];
  const float* s7 = (const float*)d_in[21];  const float* t7 = (const float*)d_in[22];
  const float* s8 = (const float*)d_in[23];  const float* t8 = (const float*)d_in[24];

  char* wsb = (char*)d_ws;
  size_t off = 0;
  auto alloc = [&](size_t bytes)->char* {
    char* p = wsb + off;
    off += (bytes + 255) & ~(size_t)255;
    return p;
  };
  int*      idx1 = (int*)alloc((size_t)BB*NN*KK*4);
  int*      idx2 = (int*)alloc((size_t)BB*NN*KK*4);
  int*      idx3 = (int*)alloc((size_t)BB*NN*KK*4);
  u64*      pkeys= (u64*)alloc((size_t)BB*NN*2*KK*8);
  float*    x1t  = (float*)alloc((size_t)BB*NN*64*4);
  float*    x2t  = (float*)alloc((size_t)BB*NN*64*4);
  float*    x3t  = (float*)alloc((size_t)BB*NN*64*4);
  float*    gsum = (float*)alloc((size_t)BB*256*4);
  unsigned* x4e  = (unsigned*)alloc((size_t)BB*512*4);
  float*    x5s  = (float*)alloc((size_t)BB*512*4);
  float*    c7   = (float*)alloc((size_t)BB*512*4);
  float*    W1T  = (float*)alloc(14*64*4);
  float*    W2T  = (float*)alloc(64*64*4);
  float*    W3T  = (float*)alloc(128*64*4);
  float*    W4T  = (float*)alloc(64*64*4);
  float*    W5T  = (float*)alloc(128*64*4);
  float*    W8T  = (float*)alloc(1024*128*4);

  prep_k<<<64,256,0,stream>>>(W1,W2,W3,W4,W5,W8, W1T,W2T,W3T,W4T,W5T,W8T);
  knn2d_k<<<BB*64*2,256,0,stream>>>(x, pkeys);
  kmerge_k<<<BB*NN/256,256,0,stream>>>(pkeys, idx1);
  edge1_k<<<BB*NN/4,256,0,stream>>>(x, idx1, W1T, W2T, s1,t1,s2,t2, x1t);
  knn64_k<<<BB*64*2,256,0,stream>>>(x1t, pkeys);
  kmerge_k<<<BB*NN/256,256,0,stream>>>(pkeys, idx2);
  edge2_k<<<BB*NN/4,256,0,stream>>>(x1t, idx2, W3T, W4T, s3,t3,s4,t4, x2t);
  knn64_k<<<BB*64*2,256,0,stream>>>(x2t, pkeys);
  kmerge_k<<<BB*NN/256,256,0,stream>>>(pkeys, idx3);
  edge3_k<<<BB*NN/4,256,0,stream>>>(x2t, idx3, W5T, s5,t5, x3t);
  hipMemsetAsync(gsum, 0, (size_t)BB*256*4 + (size_t)BB*512*4*2, stream);
  g1_k<<<256,256,0,stream>>>(W6, x1t,x2t,x3t, s6,t6, gsum);
  g2_k<<<16,256,0,stream>>>(W7, gsum, c7);
  g3_k<<<512,256,0,stream>>>(W7, x1t,x2t,x3t, c7, s7,t7, x4e, x5s);
  g4_k<<<BB,128,0,stream>>>(W8T, x4e, x5s, s8,t8, (float*)d_out);
}

// Round 9
// 1798.059 us; speedup vs baseline: 1.2980x; 1.0493x over previous
//
#include <hip/hip_runtime.h>

#define BB 8
#define NN 4096
#define KK 10
typedef unsigned long long u64;
typedef __attribute__((ext_vector_type(8))) short bf16x8;
typedef __attribute__((ext_vector_type(4))) float f32x4;

__device__ __forceinline__ float lrelu(float v){ return v >= 0.f ? v : 0.2f*v; }
__device__ __forceinline__ float bc(float v, int l){
  return __int_as_float(__builtin_amdgcn_readlane(__float_as_int(v), l));
}
__device__ __forceinline__ unsigned fenc(float f){
  unsigned u = __float_as_uint(f);
  return u ^ (((unsigned)((int)u >> 31)) | 0x80000000u);
}
__device__ __forceinline__ float fdec(unsigned e){
  return (e & 0x80000000u) ? __uint_as_float(e & 0x7fffffffu) : __uint_as_float(~e);
}
__device__ __forceinline__ u64 shflx_u64(u64 x, int d){
  unsigned lo = __shfl_xor((unsigned)x, d, 64);
  unsigned hi = __shfl_xor((unsigned)(x >> 32), d, 64);
  return ((u64)hi << 32) | lo;
}

// ---------------- weight transposes (one-time tiny prep) ----------------
__global__ __launch_bounds__(256) void prep_k(
    const float* __restrict__ W1, const float* __restrict__ W2, const float* __restrict__ W3,
    const float* __restrict__ W4, const float* __restrict__ W5, const float* __restrict__ W8,
    float* __restrict__ W1T, float* __restrict__ W2T, float* __restrict__ W3T,
    float* __restrict__ W4T, float* __restrict__ W5T, float* __restrict__ W8T)
{
  const int t = blockIdx.x*256 + threadIdx.x;
  const int stride = gridDim.x*256;
  for (int i=t; i<64*14; i+=stride){ int o=i/14, c=i%14; W1T[c*64+o]=W1[i]; }
  for (int i=t; i<64*64; i+=stride){ int o=i>>6, c=i&63; W2T[c*64+o]=W2[i]; }
  for (int i=t; i<64*128; i+=stride){ int o=i>>7, c=i&127; W3T[c*64+o]=W3[i]; }
  for (int i=t; i<64*64; i+=stride){ int o=i>>6, c=i&63; W4T[c*64+o]=W4[i]; }
  for (int i=t; i<64*128; i+=stride){ int o=i>>7, c=i&127; W5T[c*64+o]=W5[i]; }
  for (int i=t; i<128*1024; i+=stride){ int o=i>>10, c=i&1023; W8T[c*128+o]=W8[i]; }
}

// ---------------- one-time fp32 -> split bf16 (hi/lo) + squared norms ----------------
// Hoists the per-tile conversion out of knn64_k (was redone 16x per point per dispatch).
__global__ __launch_bounds__(256) void cvt_k(const float* __restrict__ xin,
    unsigned short* __restrict__ Xh, unsigned short* __restrict__ Xl, float* __restrict__ xx)
{
  const int gid = blockIdx.x*256 + threadIdx.x;   // BB*NN*8 threads
  const int p = gid >> 3, c8 = (gid & 7) << 3;
  const float* src = xin + (size_t)p*64 + c8;
  float fv[8];
  *(float4*)&fv[0] = *(const float4*)(src);
  *(float4*)&fv[4] = *(const float4*)(src + 4);
  unsigned hp[4], lp[4];
  float ssq = 0.f;
  #pragma unroll
  for (int e=0; e<4; e++){
    float f0 = fv[2*e], f1 = fv[2*e+1];
    ssq += f0*f0 + f1*f1;
    unsigned u0 = __float_as_uint(f0), u1 = __float_as_uint(f1);
    hp[e] = (u0 >> 16) | (u1 & 0xffff0000u);
    float l0 = f0 - __uint_as_float(u0 & 0xffff0000u);
    float l1 = f1 - __uint_as_float(u1 & 0xffff0000u);
    lp[e] = (__float_as_uint(l0) >> 16) | (__float_as_uint(l1) & 0xffff0000u);
  }
  *(uint4*)(Xh + (size_t)p*64 + c8) = uint4{hp[0],hp[1],hp[2],hp[3]};
  *(uint4*)(Xl + (size_t)p*64 + c8) = uint4{lp[0],lp[1],lp[2],lp[3]};
  ssq += __shfl_xor(ssq, 1, 64);
  ssq += __shfl_xor(ssq, 2, 64);
  ssq += __shfl_xor(ssq, 4, 64);
  if ((gid & 7) == 0) xx[p] = ssq;
}

// ---------------- knn over first 2 channels (candidate-split halves) ----------------
__global__ __launch_bounds__(256) void knn2d_k(const float* __restrict__ x, u64* __restrict__ pk)
{
  __shared__ float px[2048], py[2048], pxx[2048];
  const int tid = threadIdx.x;
  const int b  = blockIdx.x >> 7;
  const int qt = (blockIdx.x >> 1) & 63;
  const int h  = blockIdx.x & 1;
  const int q0 = qt*64;
  const int m0g = h*2048;
  const float* xb = x + (size_t)b*7*NN;
  for (int m = tid; m < 2048; m += 256){
    float a = xb[m0g + m], c = xb[NN + m0g + m];
    px[m] = a; py[m] = c; pxx[m] = a*a + c*c;
  }
  __syncthreads();

  const int ty = tid >> 4, tx = tid & 15;
  const int qr = ty*4;
  float qx4[4], qy4[4], q24[4];
  #pragma unroll
  for (int i=0;i<4;i++){
    float a = xb[q0+qr+i], c = xb[NN + q0+qr+i];
    qx4[i] = a; qy4[i] = c; q24[i] = a*a + c*c;
  }

  u64 bk[4][KK]; u64 tau[4];
  #pragma unroll
  for (int i=0;i<4;i++){
    tau[i] = 0ull;
    #pragma unroll
    for (int s=0;s<KK;s++) bk[i][s] = 0ull;
  }

  for (int ot=0; ot<16; ot++){
    #pragma unroll
    for (int j=0;j<8;j++){
      const int ml = ot*128 + j*16 + tx;
      const float cmx = px[ml], cmy = py[ml], cm2 = pxx[ml];
      const unsigned mk = ~(unsigned)(m0g + ml);
      #pragma unroll
      for (int i=0;i<4;i++){
        float dot = qx4[i]*cmx + qy4[i]*cmy;
        float v = (-q24[i]) - (-2.f*dot) - cm2;
        u64 key = ((u64)fenc(v) << 32) | mk;
        if (key >= tau[i]){
          if (key > bk[i][KK-1]){
            bk[i][KK-1] = key;
            #pragma unroll
            for (int s=KK-1;s>0;s--){
              if (bk[i][s] > bk[i][s-1]){ u64 t=bk[i][s]; bk[i][s]=bk[i][s-1]; bk[i][s-1]=t; }
            }
          }
        }
      }
    }
    #pragma unroll
    for (int i=0;i<4;i++){
      u64 t = bk[i][KK-1];
      t = t > shflx_u64(t,1) ? t : shflx_u64(t,1);
      t = t > shflx_u64(t,2) ? t : shflx_u64(t,2);
      t = t > shflx_u64(t,4) ? t : shflx_u64(t,4);
      t = t > shflx_u64(t,8) ? t : shflx_u64(t,8);
      tau[i] = t;
    }
  }

  #pragma unroll
  for (int i=0;i<4;i++){
    #pragma unroll
    for (int k=0;k<KK;k++){
      u64 best = bk[i][0];
      #pragma unroll
      for (int d=1; d<16; d<<=1){
        u64 o = shflx_u64(best, d);
        if (o > best) best = o;
      }
      if (bk[i][0] == best){
        #pragma unroll
        for (int s=0;s<KK-1;s++) bk[i][s] = bk[i][s+1];
        bk[i][KK-1] = 0ull;
      }
      if (tx == 0) pk[(((size_t)b*NN + q0 + qr + i)*2 + h)*KK + k] = best;
    }
  }
}

// ---------------- knn over 64 channels: split-bf16 MFMA, precomputed hi/lo ----------------
// Staging is now pure data movement: 4 coalesced uint4 loads + 4 ds_write_b128 per
// thread per tile; qxx/cxx read from precomputed xx. Distances bit-identical to r8.
__global__ __launch_bounds__(256) void knn64_k(const unsigned short* __restrict__ Xh,
    const unsigned short* __restrict__ Xl, const float* __restrict__ xx, u64* __restrict__ pk)
{
  __shared__ unsigned short Qh[64*72], Ql[64*72];   // 9216 B each (72-ch padded rows)
  __shared__ unsigned short Ch[64*72], Cl[64*72];
  __shared__ float qxx[64], cxx[64];
  const int tid = threadIdx.x;
  const int b  = blockIdx.x >> 7;
  const int qt = (blockIdx.x >> 1) & 63;
  const int h  = blockIdx.x & 1;
  const int q0 = qt*64;
  const int m0g = h*2048;
  const unsigned short* Xhb = Xh + (size_t)b*NN*64;
  const unsigned short* Xlb = Xl + (size_t)b*NN*64;
  const float* xxb = xx + (size_t)b*NN;

  const int sp = tid >> 2;          // staging point 0..63
  const int sc = (tid & 3) << 4;    // staging channel base 0,16,32,48 (ushorts)

  // ---- stage Q tile ----
  {
    const uint4* sh = (const uint4*)(Xhb + (size_t)(q0+sp)*64 + sc);
    const uint4* sl = (const uint4*)(Xlb + (size_t)(q0+sp)*64 + sc);
    uint4 h0 = sh[0], h1 = sh[1], l0 = sl[0], l1 = sl[1];
    *(uint4*)(&Qh[sp*72 + sc])     = h0;
    *(uint4*)(&Qh[sp*72 + sc + 8]) = h1;
    *(uint4*)(&Ql[sp*72 + sc])     = l0;
    *(uint4*)(&Ql[sp*72 + sc + 8]) = l1;
    if (tid < 64) qxx[tid] = xxb[q0 + tid];
  }
  __syncthreads();

  const int lane = tid & 63;
  const int w    = tid >> 6;
  const int col  = lane & 15;
  const int quad = (tid >> 4) & 3;
  const int qr   = (tid >> 4)*4;              // == w*16 + quad*4 (selection query base)
  const int aoff = (w*16 + col)*72 + quad*8;  // A-frag ushort index (kc adds +32)

  float qx4[4];
  #pragma unroll
  for (int i=0;i<4;i++) qx4[i] = qxx[qr+i];

  u64 bk[4][KK]; u64 tau[4];
  #pragma unroll
  for (int i=0;i<4;i++){
    tau[i] = 0ull;
    #pragma unroll
    for (int s=0;s<KK;s++) bk[i][s] = 0ull;
  }

  for (int ct=0; ct<32; ct++){
    const int m0 = m0g + ct*64;
    __syncthreads();
    {
      const uint4* sh = (const uint4*)(Xhb + (size_t)(m0+sp)*64 + sc);
      const uint4* sl = (const uint4*)(Xlb + (size_t)(m0+sp)*64 + sc);
      uint4 h0 = sh[0], h1 = sh[1], l0 = sl[0], l1 = sl[1];
      *(uint4*)(&Ch[sp*72 + sc])     = h0;
      *(uint4*)(&Ch[sp*72 + sc + 8]) = h1;
      *(uint4*)(&Cl[sp*72 + sc])     = l0;
      *(uint4*)(&Cl[sp*72 + sc + 8]) = l1;
      if (tid < 64) cxx[tid] = xxb[m0 + tid];
    }
    __syncthreads();

    bf16x8 Ah0 = *(const bf16x8*)(&Qh[aoff]);
    bf16x8 Ah1 = *(const bf16x8*)(&Qh[aoff+32]);
    bf16x8 Al0 = *(const bf16x8*)(&Ql[aoff]);
    bf16x8 Al1 = *(const bf16x8*)(&Ql[aoff+32]);

    #pragma unroll
    for (int j=0;j<4;j++){
      const int boff = (j*16 + col)*72 + quad*8;
      bf16x8 Bh0 = *(const bf16x8*)(&Ch[boff]);
      bf16x8 Bh1 = *(const bf16x8*)(&Ch[boff+32]);
      bf16x8 Bl0 = *(const bf16x8*)(&Cl[boff]);
      bf16x8 Bl1 = *(const bf16x8*)(&Cl[boff+32]);
      f32x4 d = {0.f,0.f,0.f,0.f};
      d = __builtin_amdgcn_mfma_f32_16x16x32_bf16(Al0, Bh0, d, 0,0,0);
      d = __builtin_amdgcn_mfma_f32_16x16x32_bf16(Ah0, Bl0, d, 0,0,0);
      d = __builtin_amdgcn_mfma_f32_16x16x32_bf16(Ah0, Bh0, d, 0,0,0);
      d = __builtin_amdgcn_mfma_f32_16x16x32_bf16(Al1, Bh1, d, 0,0,0);
      d = __builtin_amdgcn_mfma_f32_16x16x32_bf16(Ah1, Bl1, d, 0,0,0);
      d = __builtin_amdgcn_mfma_f32_16x16x32_bf16(Ah1, Bh1, d, 0,0,0);

      const int m = m0 + j*16 + col;
      const float cx = cxx[j*16 + col];
      const unsigned mk = ~(unsigned)m;
      #pragma unroll
      for (int i=0;i<4;i++){
        float v = (-qx4[i]) - (-2.f*d[i]) - cx;
        u64 key = ((u64)fenc(v) << 32) | mk;
        if (key >= tau[i]){
          if (key > bk[i][KK-1]){
            bk[i][KK-1] = key;
            #pragma unroll
            for (int s=KK-1;s>0;s--){
              if (bk[i][s] > bk[i][s-1]){ u64 t=bk[i][s]; bk[i][s]=bk[i][s-1]; bk[i][s-1]=t; }
            }
          }
        }
      }
    }
    #pragma unroll
    for (int i=0;i<4;i++){
      u64 t = bk[i][KK-1];
      t = t > shflx_u64(t,1) ? t : shflx_u64(t,1);
      t = t > shflx_u64(t,2) ? t : shflx_u64(t,2);
      t = t > shflx_u64(t,4) ? t : shflx_u64(t,4);
      t = t > shflx_u64(t,8) ? t : shflx_u64(t,8);
      tau[i] = t;
    }
  }

  #pragma unroll
  for (int i=0;i<4;i++){
    #pragma unroll
    for (int k=0;k<KK;k++){
      u64 best = bk[i][0];
      #pragma unroll
      for (int d=1; d<16; d<<=1){
        u64 o = shflx_u64(best, d);
        if (o > best) best = o;
      }
      if (bk[i][0] == best){
        #pragma unroll
        for (int s=0;s<KK-1;s++) bk[i][s] = bk[i][s+1];
        bk[i][KK-1] = 0ull;
      }
      if ((tid & 15) == 0) pk[(((size_t)b*NN + q0 + qr + i)*2 + h)*KK + k] = best;
    }
  }
}

// ---------------- merge two sorted-desc 10-key halves -> final idx ----------------
__global__ __launch_bounds__(256) void kmerge_k(const u64* __restrict__ pk, int* __restrict__ idxo)
{
  const int q = blockIdx.x*256 + threadIdx.x;   // q < BB*NN
  const u64* A = pk + (size_t)q*(2*KK);
  int* op = idxo + (size_t)q*KK;
  int ia = 0, ib = 0;
  #pragma unroll
  for (int k=0;k<KK;k++){
    u64 a = (ia < KK) ? A[ia] : 0ull;
    u64 b2 = (ib < KK) ? A[KK+ib] : 0ull;
    if (a >= b2){ op[k] = (int)(~(unsigned)a); ia++; }
    else        { op[k] = (int)(~(unsigned)b2); ib++; }
  }
}

// ---------------- edge conv 1: graph_feature1 + W1 + W2 + mean ----------------
__global__ __launch_bounds__(256) void edge1_k(const float* __restrict__ x, const int* __restrict__ idx,
    const float* __restrict__ W1T, const float* __restrict__ W2T,
    const float* __restrict__ s1, const float* __restrict__ t1,
    const float* __restrict__ s2, const float* __restrict__ t2,
    float* __restrict__ x1t)
{
  const int lane = threadIdx.x & 63;
  const int pt = (blockIdx.x << 2) + (threadIdx.x >> 6);
  const int b = pt >> 12, n = pt & 4095;
  const float* xb = x + (size_t)b*7*NN;
  float w1r[14], w2r[64];
  #pragma unroll
  for (int c=0;c<14;c++) w1r[c] = W1T[c*64 + lane];
  #pragma unroll
  for (int c=0;c<64;c++) w2r[c] = W2T[c*64 + lane];
  const float s1o=s1[lane], t1o=t1[lane], s2o=s2[lane], t2o=t2[lane];
  const float xq = (lane < 7) ? xb[lane*NN + n] : 0.f;
  const float xq0 = bc(xq,0), xq1 = bc(xq,1);
  float qy1 = 0.f;
  #pragma unroll
  for (int c=0;c<7;c++) qy1 += w1r[7+c]*bc(xq,c);
  const int* ip = idx + (size_t)pt*KK;
  float acc = 0.f;
  for (int j=0;j<KK;j++){
    const int ij = ip[j];
    const float xg = (lane < 7) ? xb[lane*NN + ij] : 0.f;
    float y1 = qy1;
    y1 += w1r[0]*(bc(xg,0) - xq0);
    y1 += w1r[1]*(bc(xg,1) - xq1);
    #pragma unroll
    for (int c=2;c<7;c++) y1 += w1r[c]*bc(xg,c);
    const float z1 = lrelu(y1*s1o + t1o);
    float p0=0.f,p1=0.f,p2=0.f,p3=0.f;
    #pragma unroll
    for (int c=0;c<64;c+=4){
      p0 += w2r[c+0]*bc(z1,c+0);
      p1 += w2r[c+1]*bc(z1,c+1);
      p2 += w2r[c+2]*bc(z1,c+2);
      p3 += w2r[c+3]*bc(z1,c+3);
    }
    acc += lrelu(((p0+p1)+(p2+p3))*s2o + t2o);
  }
  x1t[(size_t)pt*64 + lane] = acc / 10.f;
}

// ---------------- edge conv 2: graph_feature + W3 + W4 + mean ----------------
__global__ __launch_bounds__(256) void edge2_k(const float* __restrict__ xin, const int* __restrict__ idx,
    const float* __restrict__ W3T, const float* __restrict__ W4T,
    const float* __restrict__ s3, const float* __restrict__ t3,
    const float* __restrict__ s4, const float* __restrict__ t4,
    float* __restrict__ xout)
{
  const int lane = threadIdx.x & 63;
  const int pt = (blockIdx.x << 2) + (threadIdx.x >> 6);
  const int b = pt >> 12;
  float wd[64], wq[64], w4[64];
  #pragma unroll
  for (int c=0;c<64;c++) wd[c] = W3T[c*64 + lane];
  #pragma unroll
  for (int c=0;c<64;c++) wq[c] = W3T[(64+c)*64 + lane];
  #pragma unroll
  for (int c=0;c<64;c++) w4[c] = W4T[c*64 + lane];
  const float s3o=s3[lane], t3o=t3[lane], s4o=s4[lane], t4o=t4[lane];
  const float xq = xin[(size_t)pt*64 + lane];
  float a0=0.f,a1=0.f,a2=0.f,a3=0.f;
  #pragma unroll
  for (int c=0;c<64;c+=4){
    a0 += wq[c+0]*bc(xq,c+0);
    a1 += wq[c+1]*bc(xq,c+1);
    a2 += wq[c+2]*bc(xq,c+2);
    a3 += wq[c+3]*bc(xq,c+3);
  }
  const float yq = (a0+a1)+(a2+a3);
  const int* ip = idx + (size_t)pt*KK;
  float acc = 0.f;
  for (int j=0;j<KK;j++){
    const int ij = ip[j];
    const float xg = xin[((size_t)(b*NN + ij))*64 + lane];
    const float d = xg - xq;
    float p0=0.f,p1=0.f,p2=0.f,p3=0.f;
    #pragma unroll
    for (int c=0;c<64;c+=4){
      p0 += wd[c+0]*bc(d,c+0);
      p1 += wd[c+1]*bc(d,c+1);
      p2 += wd[c+2]*bc(d,c+2);
      p3 += wd[c+3]*bc(d,c+3);
    }
    const float z3 = lrelu((yq + ((p0+p1)+(p2+p3)))*s3o + t3o);
    float q0=0.f,q1=0.f,q2=0.f,q3=0.f;
    #pragma unroll
    for (int c=0;c<64;c+=4){
      q0 += w4[c+0]*bc(z3,c+0);
      q1 += w4[c+1]*bc(z3,c+1);
      q2 += w4[c+2]*bc(z3,c+2);
      q3 += w4[c+3]*bc(z3,c+3);
    }
    acc += lrelu(((q0+q1)+(q2+q3))*s4o + t4o);
  }
  xout[(size_t)pt*64 + lane] = acc / 10.f;
}

// ---------------- edge conv 3: graph_feature + W5 + mean ----------------
__global__ __launch_bounds__(256) void edge3_k(const float* __restrict__ xin, const int* __restrict__ idx,
    const float* __restrict__ W5T,
    const float* __restrict__ s5, const float* __restrict__ t5,
    float* __restrict__ xout)
{
  const int lane = threadIdx.x & 63;
  const int pt = (blockIdx.x << 2) + (threadIdx.x >> 6);
  const int b = pt >> 12;
  float wd[64], wq[64];
  #pragma unroll
  for (int c=0;c<64;c++) wd[c] = W5T[c*64 + lane];
  #pragma unroll
  for (int c=0;c<64;c++) wq[c] = W5T[(64+c)*64 + lane];
  const float s5o=s5[lane], t5o=t5[lane];
  const float xq = xin[(size_t)pt*64 + lane];
  float a0=0.f,a1=0.f,a2=0.f,a3=0.f;
  #pragma unroll
  for (int c=0;c<64;c+=4){
    a0 += wq[c+0]*bc(xq,c+0);
    a1 += wq[c+1]*bc(xq,c+1);
    a2 += wq[c+2]*bc(xq,c+2);
    a3 += wq[c+3]*bc(xq,c+3);
  }
  const float yq = (a0+a1)+(a2+a3);
  const int* ip = idx + (size_t)pt*KK;
  float acc = 0.f;
  for (int j=0;j<KK;j++){
    const int ij = ip[j];
    const float xg = xin[((size_t)(b*NN + ij))*64 + lane];
    const float d = xg - xq;
    float p0=0.f,p1=0.f,p2=0.f,p3=0.f;
    #pragma unroll
    for (int c=0;c<64;c+=4){
      p0 += wd[c+0]*bc(d,c+0);
      p1 += wd[c+1]*bc(d,c+1);
      p2 += wd[c+2]*bc(d,c+2);
      p3 += wd[c+3]*bc(d,c+3);
    }
    acc += lrelu((yq + ((p0+p1)+(p2+p3)))*s5o + t5o);
  }
  xout[(size_t)pt*64 + lane] = acc / 10.f;
}

// ---------------- G1: h6 = lrelu(W6@z), accumulate sum over N ----------------
__global__ __launch_bounds__(256) void g1_k(const float* __restrict__ W6,
   const float* __restrict__ x1t, const float* __restrict__ x2t, const float* __restrict__ x3t,
   const float* __restrict__ s6, const float* __restrict__ t6, float* __restrict__ gsum)
{
  __shared__ float Wl[16*132];
  __shared__ float Zl[16*260];
  const int tid = threadIdx.x;
  const int rb = blockIdx.x & 1;
  const int nt = (blockIdx.x >> 1) & 15;
  const int b  = blockIdx.x >> 5;
  const int r0 = rb*128;
  const int n0 = nt*256;
  const int ty = tid >> 4, tx = tid & 15;
  float acc[8][16];
  #pragma unroll
  for (int i=0;i<8;i++){
    #pragma unroll
    for (int j=0;j<16;j++) acc[i][j] = 0.f;
  }
  for (int kc=0; kc<12; kc++){
    __syncthreads();
    {
      const int r = tid >> 1, h = tid & 1;
      const float4* wp = (const float4*)(W6 + (size_t)(r0 + r)*192 + kc*16 + h*8);
      float tmp[8];
      *(float4*)&tmp[0] = wp[0];
      *(float4*)&tmp[4] = wp[1];
      #pragma unroll
      for (int u=0;u<8;u++) Wl[(h*8+u)*132 + r] = tmp[u];
    }
    {
      const float* arr = (kc < 4) ? x1t : (kc < 8) ? x2t : x3t;
      const int chofs = (kc & 3)*16;
      const float4* zp = (const float4*)(arr + ((size_t)(b*NN) + n0 + tid)*64 + chofs);
      float tmp[16];
      *(float4*)&tmp[0]  = zp[0];
      *(float4*)&tmp[4]  = zp[1];
      *(float4*)&tmp[8]  = zp[2];
      *(float4*)&tmp[12] = zp[3];
      #pragma unroll
      for (int u=0;u<16;u++) Zl[u*260 + tid] = tmp[u];
    }
    __syncthreads();
    #pragma unroll 4
    for (int k=0;k<16;k++){
      float wv[8], zv[16];
      *(float4*)&wv[0] = *(const float4*)(&Wl[k*132 + ty*8]);
      *(float4*)&wv[4] = *(const float4*)(&Wl[k*132 + ty*8 + 4]);
      #pragma unroll
      for (int jg=0;jg<4;jg++)
        *(float4*)&zv[jg*4] = *(const float4*)(&Zl[k*260 + jg*64 + tx*4]);
      #pragma unroll
      for (int i=0;i<8;i++){
        #pragma unroll
        for (int j=0;j<16;j++) acc[i][j] += wv[i]*zv[j];
      }
    }
  }
  #pragma unroll
  for (int i=0;i<8;i++){
    const int row = r0 + ty*8 + i;
    const float sv = s6[row], tv = t6[row];
    float sum = 0.f;
    #pragma unroll
    for (int j=0;j<16;j++) sum += lrelu(acc[i][j]*sv + tv);
    #pragma unroll
    for (int d=1; d<16; d<<=1) sum += __shfl_xor(sum, d, 64);
    if ((tid & 15) == 0) atomicAdd(&gsum[b*256 + row], sum);
  }
}

// ---------------- G2: c7 = W7[:, :256] @ (gsum/4096) ----------------
__global__ __launch_bounds__(256) void g2_k(const float* __restrict__ W7,
   const float* __restrict__ gsum, float* __restrict__ c7)
{
  const int b = blockIdx.x >> 1;
  const int o = (blockIdx.x & 1)*256 + threadIdx.x;
  const float* wr = W7 + (size_t)o*448;
  const float* gb = gsum + b*256;
  float a0=0.f,a1=0.f,a2=0.f,a3=0.f;
  #pragma unroll 4
  for (int c=0;c<256;c+=4){
    a0 += wr[c+0]*gb[c+0]; a1 += wr[c+1]*gb[c+1];
    a2 += wr[c+2]*gb[c+2]; a3 += wr[c+3]*gb[c+3];
  }
  c7[b*512+o] = ((a0+a1)+(a2+a3)) * (1.f/4096.f);
}

// ---------------- G3: h7 = lrelu((W7[:,256:]@z + c7)) -> max/sum over N ----------------
__global__ __launch_bounds__(256) void g3_k(const float* __restrict__ W7,
   const float* __restrict__ x1t, const float* __restrict__ x2t, const float* __restrict__ x3t,
   const float* __restrict__ c7, const float* __restrict__ s7, const float* __restrict__ t7,
   unsigned* __restrict__ x4e, float* __restrict__ x5s)
{
  __shared__ float Wl[16*132];
  __shared__ float Zl[16*260];
  const int tid = threadIdx.x;
  const int rb = blockIdx.x & 3;
  const int nt = (blockIdx.x >> 2) & 15;
  const int b  = blockIdx.x >> 6;
  const int r0 = rb*128;
  const int n0 = nt*256;
  const int ty = tid >> 4, tx = tid & 15;
  float acc[8][16];
  #pragma unroll
  for (int i=0;i<8;i++){
    #pragma unroll
    for (int j=0;j<16;j++) acc[i][j] = 0.f;
  }
  for (int kc=0; kc<12; kc++){
    __syncthreads();
    {
      const int r = tid >> 1, h = tid & 1;
      const float4* wp = (const float4*)(W7 + (size_t)(r0 + r)*448 + 256 + kc*16 + h*8);
      float tmp[8];
      *(float4*)&tmp[0] = wp[0];
      *(float4*)&tmp[4] = wp[1];
      #pragma unroll
      for (int u=0;u<8;u++) Wl[(h*8+u)*132 + r] = tmp[u];
    }
    {
      const float* arr = (kc < 4) ? x1t : (kc < 8) ? x2t : x3t;
      const int chofs = (kc & 3)*16;
      const float4* zp = (const float4*)(arr + ((size_t)(b*NN) + n0 + tid)*64 + chofs);
      float tmp[16];
      *(float4*)&tmp[0]  = zp[0];
      *(float4*)&tmp[4]  = zp[1];
      *(float4*)&tmp[8]  = zp[2];
      *(float4*)&tmp[12] = zp[3];
      #pragma unroll
      for (int u=0;u<16;u++) Zl[u*260 + tid] = tmp[u];
    }
    __syncthreads();
    #pragma unroll 4
    for (int k=0;k<16;k++){
      float wv[8], zv[16];
      *(float4*)&wv[0] = *(const float4*)(&Wl[k*132 + ty*8]);
      *(float4*)&wv[4] = *(const float4*)(&Wl[k*132 + ty*8 + 4]);
      #pragma unroll
      for (int jg=0;jg<4;jg++)
        *(float4*)&zv[jg*4] = *(const float4*)(&Zl[k*260 + jg*64 + tx*4]);
      #pragma unroll
      for (int i=0;i<8;i++){
        #pragma unroll
        for (int j=0;j<16;j++) acc[i][j] += wv[i]*zv[j];
      }
    }
  }
  #pragma unroll
  for (int i=0;i<8;i++){
    const int row = r0 + ty*8 + i;
    const float c7v = c7[b*512 + row];
    const float sv = s7[row], tv = t7[row];
    float mx = -__builtin_inff(), sum = 0.f;
    #pragma unroll
    for (int j=0;j<16;j++){
      float h = lrelu((acc[i][j] + c7v)*sv + tv);
      mx = fmaxf(mx, h); sum += h;
    }
    #pragma unroll
    for (int d=1; d<16; d<<=1){
      sum += __shfl_xor(sum, d, 64);
      mx = fmaxf(mx, __shfl_xor(mx, d, 64));
    }
    if ((tid & 15) == 0){
      atomicAdd(&x5s[b*512 + row], sum);
      atomicMax(&x4e[b*512 + row], fenc(mx));
    }
  }
}

// ---------------- G4: final linear ----------------
__global__ __launch_bounds__(128) void g4_k(const float* __restrict__ W8T,
  const unsigned* __restrict__ x4e, const float* __restrict__ x5s,
  const float* __restrict__ s8, const float* __restrict__ t8, float* __restrict__ out)
{
  const int b = blockIdx.x, j = threadIdx.x;
  float a0 = 0.f, a1 = 0.f;
  for (int o=0;o<512;o++){
    a0 += W8T[o*128 + j] * fdec(x4e[b*512 + o]);
    a1 += W8T[(512+o)*128 + j] * (x5s[b*512 + o] * (1.f/4096.f));
  }
  const float y = a0 + a1;
  out[b*128 + j] = lrelu(y*s8[j] + t8[j]);
}

extern "C" void kernel_launch(void* const* d_in, const int* in_sizes, int n_in,
                              void* d_out, int out_size, void* d_ws, size_t ws_size,
                              hipStream_t stream) {
  (void)in_sizes; (void)n_in; (void)out_size; (void)ws_size;
  const float* x  = (const float*)d_in[0];
  const float* W1 = (const float*)d_in[1];
  const float* W2 = (const float*)d_in[2];
  const float* W3 = (const float*)d_in[3];
  const float* W4 = (const float*)d_in[4];
  const float* W5 = (const float*)d_in[5];
  const float* W6 = (const float*)d_in[6];
  const float* W7 = (const float*)d_in[7];
  const float* W8 = (const float*)d_in[8];
  const float* s1 = (const float*)d_in[9];   const float* t1 = (const float*)d_in[10];
  const float* s2 = (const float*)d_in[11];  const float* t2 = (const float*)d_in[12];
  const float* s3 = (const float*)d_in[13];  const float* t3 = (const float*)d_in[14];
  const float* s4 = (const float*)d_in[15];  const float* t4 = (const float*)d_in[16];
  const float* s5 = (const float*)d_in[17];  const float* t5 = (const float*)d_in[18];
  const float* s6 = (const float*)d_in[19];  const float* t6 = (const float*)d_in[20];
  const float* s7 = (const float*)d_in[21];  const float* t7 = (const float*)d_in[22];
  const float* s8 = (const float*)d_in[23];  const float* t8 = (const float*)d_in[24];

  char* wsb = (char*)d_ws;
  size_t off = 0;
  auto alloc = [&](size_t bytes)->char* {
    char* p = wsb + off;
    off += (bytes + 255) & ~(size_t)255;
    return p;
  };
  int*      idx1 = (int*)alloc((size_t)BB*NN*KK*4);
  int*      idx2 = (int*)alloc((size_t)BB*NN*KK*4);
  int*      idx3 = (int*)alloc((size_t)BB*NN*KK*4);
  u64*      pkeys= (u64*)alloc((size_t)BB*NN*2*KK*8);
  float*    x1t  = (float*)alloc((size_t)BB*NN*64*4);
  float*    x2t  = (float*)alloc((size_t)BB*NN*64*4);
  float*    x3t  = (float*)alloc((size_t)BB*NN*64*4);
  unsigned short* Xh = (unsigned short*)alloc((size_t)BB*NN*64*2);
  unsigned short* Xl = (unsigned short*)alloc((size_t)BB*NN*64*2);
  float*    xxb  = (float*)alloc((size_t)BB*NN*4);
  float*    gsum = (float*)alloc((size_t)BB*256*4);
  unsigned* x4e  = (unsigned*)alloc((size_t)BB*512*4);
  float*    x5s  = (float*)alloc((size_t)BB*512*4);
  float*    c7   = (float*)alloc((size_t)BB*512*4);
  float*    W1T  = (float*)alloc(14*64*4);
  float*    W2T  = (float*)alloc(64*64*4);
  float*    W3T  = (float*)alloc(128*64*4);
  float*    W4T  = (float*)alloc(64*64*4);
  float*    W5T  = (float*)alloc(128*64*4);
  float*    W8T  = (float*)alloc(1024*128*4);

  prep_k<<<64,256,0,stream>>>(W1,W2,W3,W4,W5,W8, W1T,W2T,W3T,W4T,W5T,W8T);
  knn2d_k<<<BB*64*2,256,0,stream>>>(x, pkeys);
  kmerge_k<<<BB*NN/256,256,0,stream>>>(pkeys, idx1);
  edge1_k<<<BB*NN/4,256,0,stream>>>(x, idx1, W1T, W2T, s1,t1,s2,t2, x1t);
  cvt_k<<<BB*NN*8/256,256,0,stream>>>(x1t, Xh, Xl, xxb);
  knn64_k<<<BB*64*2,256,0,stream>>>(Xh, Xl, xxb, pkeys);
  kmerge_k<<<BB*NN/256,256,0,stream>>>(pkeys, idx2);
  edge2_k<<<BB*NN/4,256,0,stream>>>(x1t, idx2, W3T, W4T, s3,t3,s4,t4, x2t);
  cvt_k<<<BB*NN*8/256,256,0,stream>>>(x2t, Xh, Xl, xxb);
  knn64_k<<<BB*64*2,256,0,stream>>>(Xh, Xl, xxb, pkeys);
  kmerge_k<<<BB*NN/256,256,0,stream>>>(pkeys, idx3);
  edge3_k<<<BB*NN/4,256,0,stream>>>(x2t, idx3, W5T, s5,t5, x3t);
  hipMemsetAsync(gsum, 0, (size_t)BB*256*4 + (size_t)BB*512*4*2, stream);
  g1_k<<<256,256,0,stream>>>(W6, x1t,x2t,x3t, s6,t6, gsum);
  g2_k<<<16,256,0,stream>>>(W7, gsum, c7);
  g3_k<<<512,256,0,stream>>>(W7, x1t,x2t,x3t, c7, s7,t7, x4e, x5s);
  g4_k<<<BB,128,0,stream>>>(W8T, x4e, x5s, s8,t8, (float*)d_out);
}